// Round 1
// baseline (144.122 us; speedup 1.0000x reference)
//
#include <hip/hip_runtime.h>
#include <hip/hip_bf16.h>

// TransformerEncoderReadout: only the picked atom's output row is needed.
// Algorithmic reduction:
//   score(i,h) = x_i . QK[b,h,:] + QBK[b,h],  QK = (xp.Wq+bq).Wk^T (per head)
//   ctx(h,:)   = (sum_i attn(i,h) x_i) . Wv_h + bv_h          (softmax sums to 1)
//   attn_out   = sum_h WX[h,:] . WVO_h + (bv.Wo) + bo,  WVO_h = Wv_h . Wo_h
// Then residual+LN, FFN, residual+LN on [512,128] rows only.

#define BMOL 512
#define DIM 128
#define NH 8
#define FFD 512

// ---------------- prep: segment offsets + fused weights ----------------
__global__ __launch_bounds__(256) void k_prep(
    const float* __restrict__ Wq, const float* __restrict__ bq,
    const float* __restrict__ Wk, const float* __restrict__ bk,
    const float* __restrict__ Wv, const float* __restrict__ Wo,
    const float* __restrict__ bo, const float* __restrict__ bv,
    const int* __restrict__ mol, int N, int noff,
    int* __restrict__ offs, float* __restrict__ WQK, float* __restrict__ WVO,
    float* __restrict__ bqk, float* __restrict__ wqbk,
    float* __restrict__ bqbk, float* __restrict__ bvo)
{
    int bid = blockIdx.x, t = threadIdx.x;
    if (bid < noff) {                       // segment offsets
        int i = bid * 256 + t;
        if (i < N) {
            if (i == 0) { offs[0] = 0; offs[BMOL] = N; }
            else if (mol[i] != mol[i-1]) offs[mol[i]] = i;
        }
        return;
    }
    bid -= noff;
    if (bid < 512) {                        // WQK[d'*1024 + h*128 + d] = sum_kd Wq[d',h,kd]*Wk[d,h,kd]
        int o = bid * 256 + t;
        int dp = o >> 10, h = (o >> 7) & 7, d = o & 127;
        const float4* a = (const float4*)(Wq + dp * 1024 + h * 128);
        const float4* b4 = (const float4*)(Wk + d * 1024 + h * 128);
        float acc = 0.f;
        #pragma unroll 8
        for (int k = 0; k < 32; ++k) {
            float4 x = a[k], y = b4[k];
            acc += x.x*y.x + x.y*y.y + x.z*y.z + x.w*y.w;
        }
        WQK[o] = acc;
        return;
    }
    bid -= 512;
    if (bid < 512) {                        // WVO[(h*128+d)*128 + d'] = sum_kd Wv[d,h,kd]*Wo[h,kd,d']
        int o = bid * 256 + t;
        int dp = o & 127, hd = o >> 7;
        int h = hd >> 7, d = hd & 127;
        const float* av = Wv + d * 1024 + h * 128;
        const float* wo = Wo + (h * 128) * 128 + dp;
        float acc = 0.f;
        #pragma unroll 4
        for (int kd = 0; kd < 128; ++kd) acc += av[kd] * wo[kd * 128];
        WVO[o] = acc;
        return;
    }
    bid -= 512;
    if (bid < 4) {                          // bqk[h*128+d] = sum_kd bq[h,kd]*Wk[d,h,kd]
        int o = bid * 256 + t;
        int h = o >> 7, d = o & 127;
        const float* a = bq + h * 128;
        const float* w = Wk + d * 1024 + h * 128;
        float acc = 0.f;
        #pragma unroll 4
        for (int kd = 0; kd < 128; ++kd) acc += a[kd] * w[kd];
        bqk[o] = acc;
        return;
    }
    bid -= 4;
    if (bid < 4) {                          // wqbk[d'*8+h] = sum_kd Wq[d',h,kd]*bk[h,kd]
        int o = bid * 256 + t;
        int dp = o >> 3, h = o & 7;
        const float* a = Wq + dp * 1024 + h * 128;
        const float* w = bk + h * 128;
        float acc = 0.f;
        #pragma unroll 4
        for (int kd = 0; kd < 128; ++kd) acc += a[kd] * w[kd];
        wqbk[o] = acc;
        return;
    }
    // last block: bvo[d'] = bo[d'] + sum_hk bv[hk]*Wo[hk,d'];  bqbk[h] = bq_h . bk_h
    if (t < 128) {
        float acc = bo[t];
        for (int hk = 0; hk < 1024; ++hk) acc += bv[hk] * Wo[hk * 128 + t];
        bvo[t] = acc;
    } else if (t < 136) {
        int h = t - 128;
        float acc = 0.f;
        for (int kd = 0; kd < 128; ++kd) acc += bq[h * 128 + kd] * bk[h * 128 + kd];
        bqbk[h] = acc;
    }
}

// ---------------- gather picked rows + QBK ----------------
__global__ __launch_bounds__(256) void k_gather_qbk(
    const float* __restrict__ AF, const int* __restrict__ picked,
    const int* __restrict__ offs, const float* __restrict__ wqbk,
    const float* __restrict__ bqbk, float* __restrict__ XP, float* __restrict__ QBK)
{
    int bid = blockIdx.x, t = threadIdx.x;
    if (bid < 256) {                        // XP[b][d]
        int o = bid * 256 + t;
        int b = o >> 7, d = o & 127;
        int src = offs[b] + picked[b];
        XP[o] = AF[(size_t)src * 128 + d];
        return;
    }
    bid -= 256;                             // QBK[b][h] = xp . wqbk[:,h] + bqbk[h]
    int o = bid * 256 + t;                  // 4096
    int b = o >> 3, h = o & 7;
    int src = offs[b] + picked[b];
    const float* x = AF + (size_t)src * 128;
    float acc = bqbk[h];
    for (int dp = 0; dp < 128; ++dp) acc += x[dp] * wqbk[dp * 8 + h];
    QBK[o] = acc;
}

// ---------------- batched row GEMV: out[r,c] = sum_k A[r,k] W[k,c] ----------------
// Block: 256 threads = TR row-groups x NCB cols; each thread does RPT rows.
// A-reads are wave-uniform (scalar-load friendly); W reads coalesced.
// gridDim.y > 1 => split-K partials written to out[(y*512+r)*NC + c] (no bias).
template<int NC, int KB, int RPT, bool RELU>
__global__ __launch_bounds__(256) void gemv_rows(
    const float* __restrict__ A, int lda,
    const float* __restrict__ W,
    const float* __restrict__ bias,
    float* __restrict__ out)
{
    constexpr int NCB = NC < 256 ? NC : 256;
    constexpr int TR  = 256 / NCB;
    constexpr int CCH = NC / NCB;
    int bx = blockIdx.x;
    int rblk = bx / CCH, cch = bx - rblk * CCH;
    int t = threadIdx.x;
    int c = (t & (NCB - 1)) + cch * NCB;
    int rr = (TR == 1) ? 0 : (t >> 7);      // NCB==128 => t>>7, wave-uniform
    int r0 = rblk * (TR * RPT) + rr * RPT;
    int koff = blockIdx.y * KB;
    const float* Ap = A + (size_t)r0 * lda + koff;
    const float* Wp = W + (size_t)koff * NC + c;
    float acc[RPT];
    #pragma unroll
    for (int i = 0; i < RPT; ++i) acc[i] = 0.f;
    #pragma unroll 4
    for (int k = 0; k < KB; ++k) {
        float w = Wp[(size_t)k * NC];
        #pragma unroll
        for (int i = 0; i < RPT; ++i) acc[i] += Ap[(size_t)i * lda + k] * w;
    }
    if (gridDim.y == 1) {
        float b = bias ? bias[c] : 0.f;
        #pragma unroll
        for (int i = 0; i < RPT; ++i) {
            float v = acc[i] + b;
            if (RELU) v = fmaxf(v, 0.f);
            out[(size_t)(r0 + i) * NC + c] = v;
        }
    } else {
        float* po = out + (size_t)blockIdx.y * BMOL * NC;
        #pragma unroll
        for (int i = 0; i < RPT; ++i) po[(size_t)(r0 + i) * NC + c] = acc[i];
    }
}

// ---------------- per-molecule attention: scores -> softmax -> WX ----------------
__global__ __launch_bounds__(256) void k_attn(
    const float* __restrict__ AF, const float* __restrict__ QK,
    const float* __restrict__ QBK, const int* __restrict__ offs,
    float* __restrict__ WX)
{
    int b = blockIdx.x, t = threadIdx.x;
    int o0 = offs[b], cnt = offs[b + 1] - o0;
    __shared__ float s[1024];               // [atom][head]
    __shared__ float mh[8], lh[8];
    const float scale = 0.08838834764831843f;   // 1/sqrt(128)
    int np = cnt * 8;
    for (int p = t; p < np; p += 256) {
        int i = p >> 3, h = p & 7;
        const float4* xr = (const float4*)(AF + (size_t)(o0 + i) * 128);
        const float4* qr = (const float4*)(QK + (size_t)b * 1024 + h * 128);
        float acc = 0.f;
        #pragma unroll 8
        for (int d = 0; d < 32; ++d) {
            float4 xv = xr[d], qv = qr[d];
            acc += xv.x*qv.x + xv.y*qv.y + xv.z*qv.z + xv.w*qv.w;
        }
        s[p] = (acc + QBK[b * 8 + h]) * scale;
    }
    __syncthreads();
    {   // softmax stats: 32 lanes per head
        int h = t >> 5, lane = t & 31;
        float m = -1e30f;
        for (int i = lane; i < cnt; i += 32) m = fmaxf(m, s[i * 8 + h]);
        #pragma unroll
        for (int off = 16; off; off >>= 1) m = fmaxf(m, __shfl_xor(m, off));
        float l = 0.f;
        for (int i = lane; i < cnt; i += 32) l += __expf(s[i * 8 + h] - m);
        #pragma unroll
        for (int off = 16; off; off >>= 1) l += __shfl_xor(l, off);
        if (lane == 0) { mh[h] = m; lh[h] = 1.f / l; }
    }
    __syncthreads();
    for (int p = t; p < np; p += 256) {
        int hh = p & 7;
        s[p] = __expf(s[p] - mh[hh]) * lh[hh];
    }
    __syncthreads();
    {   // WX[h][d] = sum_i attn(i,h) x_i[d]; thread = (head, 4-wide d chunk)
        int hw = t >> 5, q = t & 31;
        float4 a4 = {0.f, 0.f, 0.f, 0.f};
        for (int i = 0; i < cnt; ++i) {
            float sv = s[i * 8 + hw];
            float4 xv = ((const float4*)(AF + (size_t)(o0 + i) * 128))[q];
            a4.x += sv * xv.x; a4.y += sv * xv.y; a4.z += sv * xv.z; a4.w += sv * xv.w;
        }
        ((float4*)(WX + (size_t)b * 1024 + hw * 128))[q] = a4;
    }
}

// ---------------- reduce split-K partials + bias + residual + LayerNorm ----------------
__global__ __launch_bounds__(128) void k_reduce_ln(
    const float* __restrict__ part, int ks,
    const float* __restrict__ bias, const float* __restrict__ resid,
    const float* __restrict__ g, const float* __restrict__ be,
    float* __restrict__ out)
{
    int r = blockIdx.x, c = threadIdx.x;
    float v = bias[c] + resid[(size_t)r * 128 + c];
    for (int k = 0; k < ks; ++k) v += part[((size_t)k * BMOL + r) * 128 + c];
    float sm = v, sq = v * v;
    #pragma unroll
    for (int off = 32; off; off >>= 1) {
        sm += __shfl_xor(sm, off);
        sq += __shfl_xor(sq, off);
    }
    __shared__ float red[2][2];
    int wid = c >> 6;
    if ((c & 63) == 0) { red[wid][0] = sm; red[wid][1] = sq; }
    __syncthreads();
    float S = red[0][0] + red[1][0], Q = red[0][1] + red[1][1];
    float m = S * (1.f / 128.f);
    float var = Q * (1.f / 128.f) - m * m;
    out[(size_t)r * 128 + c] = (v - m) * rsqrtf(var + 1e-3f) * g[c] + be[c];
}

extern "C" void kernel_launch(void* const* d_in, const int* in_sizes, int n_in,
                              void* d_out, int out_size, void* d_ws, size_t ws_size,
                              hipStream_t stream) {
    const float* AF  = (const float*)d_in[0];
    const float* Wq  = (const float*)d_in[1];
    const float* bq  = (const float*)d_in[2];
    const float* Wk  = (const float*)d_in[3];
    const float* bk  = (const float*)d_in[4];
    const float* Wv  = (const float*)d_in[5];
    const float* bv  = (const float*)d_in[6];
    const float* Wo  = (const float*)d_in[7];
    const float* bo  = (const float*)d_in[8];
    const float* W1  = (const float*)d_in[9];
    const float* b1  = (const float*)d_in[10];
    const float* W2  = (const float*)d_in[11];
    const float* b2  = (const float*)d_in[12];
    const float* g1  = (const float*)d_in[13];
    const float* be1 = (const float*)d_in[14];
    const float* g2  = (const float*)d_in[15];
    const float* be2 = (const float*)d_in[16];
    const int* mol    = (const int*)d_in[17];
    const int* picked = (const int*)d_in[18];
    int N = in_sizes[0] / 128;
    int noff = (N + 255) / 256;

    char* ws = (char*)d_ws;
    int*   offs = (int*)ws;
    float* WQK  = (float*)(ws + 4096);
    float* WVO  = (float*)(ws + 528384);
    float* bqk  = (float*)(ws + 1052672);
    float* wqbk = (float*)(ws + 1056768);
    float* bqbk = (float*)(ws + 1060864);
    float* bvo  = (float*)(ws + 1061120);
    float* XP   = (float*)(ws + 1061632);
    float* QKb  = (float*)(ws + 1323776);
    float* QBK  = (float*)(ws + 3420928);
    float* WX   = (float*)(ws + 3437312);
    float* P1   = (float*)(ws + 5534464);
    float* H1   = (float*)(ws + 6583040);
    float* MID  = (float*)(ws + 6845184);
    float* P2   = (float*)(ws + 7893760);

    k_prep<<<noff + 1033, 256, 0, stream>>>(Wq, bq, Wk, bk, Wv, Wo, bo, bv,
                                            mol, N, noff,
                                            offs, WQK, WVO, bqk, wqbk, bqbk, bvo);
    k_gather_qbk<<<272, 256, 0, stream>>>(AF, picked, offs, wqbk, bqbk, XP, QBK);
    // QK[b, h*128+d] = xp . WQK + bqk : M=512,K=128,N=1024
    gemv_rows<1024, 128, 4, false><<<dim3(512, 1), 256, 0, stream>>>(XP, 128, WQK, bqk, QKb);
    k_attn<<<BMOL, 256, 0, stream>>>(AF, QKb, QBK, offs, WX);
    // attn_out partials: WX[512,1024] x WVO[1024,128], split-K 4x256
    gemv_rows<128, 256, 4, false><<<dim3(64, 4), 256, 0, stream>>>(WX, 1024, WVO, nullptr, P1);
    k_reduce_ln<<<BMOL, 128, 0, stream>>>(P1, 4, bvo, XP, g1, be1, H1);
    // FFN1: H1[512,128] x W1[128,512] + b1, relu
    gemv_rows<512, 128, 4, true><<<dim3(256, 1), 256, 0, stream>>>(H1, 128, W1, b1, MID);
    // FFN2 partials: MID[512,512] x W2[512,128], split-K 4x128
    gemv_rows<128, 128, 4, false><<<dim3(64, 4), 256, 0, stream>>>(MID, 512, W2, nullptr, P2);
    k_reduce_ln<<<BMOL, 128, 0, stream>>>(P2, 4, b2, H1, g2, be2, (float*)d_out);
}

// Round 2
// 111.359 us; speedup vs baseline: 1.2942x; 1.2942x over previous
//
#include <hip/hip_runtime.h>
#include <hip/hip_bf16.h>

// TransformerEncoderReadout: only the picked atom's output row is needed.
//   q        = AF[picked_row] . Wq + bq                       [512,1024]
//   QK[b,h,] = q[b,h,:] . WkT_h          (WkT = Wk transposed per head)
//   s(i,h)   = (x_i . QK[b,h,:] + q.bk_h)/sqrt(128); softmax over i
//   WX[h,:]  = sum_i attn(i,h) x_i       (softmax sums to 1 -> bv folds out)
//   attn_out = WX . WVO + (bv.Wo) + bo,  WVO_h = Wv_h . Wo_h
// Then residual+LN, FFN, residual+LN on the 512 picked rows only.

#define BMOL 512

// ---------------- k1: offsets + WkT transpose + WVO + bvo partials ----------------
__global__ __launch_bounds__(256) void k_prep(
    const float* __restrict__ Wk, const float* __restrict__ Wv,
    const float* __restrict__ Wo, const float* __restrict__ bv,
    const int* __restrict__ mol, int N, int noff,
    int* __restrict__ offs, float* __restrict__ WkT,
    float* __restrict__ WVO, float* __restrict__ bvoP)
{
    __shared__ float sh[32 * 33];
    int bid = blockIdx.x, t = threadIdx.x;
    if (bid < noff) {                       // segment offsets from sorted mol ids
        int i = bid * 256 + t;
        if (i < N) {
            if (i == 0) { offs[0] = 0; offs[BMOL] = N; }
            else if (mol[i] != mol[i - 1]) offs[mol[i]] = i;
        }
        return;
    }
    bid -= noff;
    if (bid < 128) {                        // WkT[h][kd][d] = Wk[d,h,kd], 32x32 LDS tiles
        int h = bid >> 4, tile = bid & 15;
        int td = tile >> 2, tk = tile & 3;
        int tx = t & 31, ty = t >> 5;
        #pragma unroll
        for (int rr = 0; rr < 4; ++rr) {
            int r = ty + rr * 8;            // d-local
            sh[r * 33 + tx] = Wk[(size_t)(td * 32 + r) * 1024 + h * 128 + tk * 32 + tx];
        }
        __syncthreads();
        #pragma unroll
        for (int rr = 0; rr < 4; ++rr) {
            int c = ty + rr * 8;            // kd-local
            WkT[(size_t)h * 16384 + (tk * 32 + c) * 128 + td * 32 + tx] = sh[tx * 33 + c];
        }
        return;
    }
    bid -= 128;
    if (bid < 128) {                        // WVO[(h*128+d)][d'] = sum_kd Wv[d,h,kd]*Wo[h,kd,d']
        int h = bid >> 4, rb = bid & 15;
        int rg = t >> 7, c = t & 127;
        int d0 = rb * 8 + rg * 4;
        const float* a = Wv + (size_t)d0 * 1024 + h * 128;   // rows contiguous in kd
        const float* w = Wo + (size_t)h * 16384 + c;         // coalesced in c
        float acc[4] = {0.f, 0.f, 0.f, 0.f};
        #pragma unroll 4
        for (int kd = 0; kd < 128; ++kd) {
            float wv = w[(size_t)kd * 128];
            #pragma unroll
            for (int i = 0; i < 4; ++i) acc[i] += a[(size_t)i * 1024 + kd] * wv;
        }
        #pragma unroll
        for (int i = 0; i < 4; ++i) WVO[(size_t)(h * 128 + d0 + i) * 128 + c] = acc[i];
        return;
    }
    bid -= 128;                             // bvoP[j][d'] = sum_{hk in j-th 128} bv[hk]*Wo[hk,d']
    {
        int half = t >> 7, c = t & 127;
        float acc = 0.f;
        #pragma unroll 4
        for (int kk = 0; kk < 64; ++kk) {
            int k = bid * 128 + half * 64 + kk;
            acc += bv[k] * Wo[(size_t)k * 128 + c];
        }
        sh[half * 128 + c] = acc;
        __syncthreads();
        if (t < 128) bvoP[bid * 128 + t] = sh[t] + sh[128 + t];
    }
}

// ---------------- k2: q = AF[picked rows] . Wq + bq ----------------
__global__ __launch_bounds__(256) void k_q(
    const float* __restrict__ AF, const int* __restrict__ offs,
    const int* __restrict__ picked, const float* __restrict__ Wq,
    const float* __restrict__ bq, float* __restrict__ q)
{
    int bx = blockIdx.x, t = threadIdx.x;
    int rblk = bx >> 2, cch = bx & 3;
    int r0 = rblk * 4;
    int c = cch * 256 + t;
    const float* x0 = AF + (size_t)(offs[r0 + 0] + picked[r0 + 0]) * 128;
    const float* x1 = AF + (size_t)(offs[r0 + 1] + picked[r0 + 1]) * 128;
    const float* x2 = AF + (size_t)(offs[r0 + 2] + picked[r0 + 2]) * 128;
    const float* x3 = AF + (size_t)(offs[r0 + 3] + picked[r0 + 3]) * 128;
    float a0 = 0.f, a1 = 0.f, a2 = 0.f, a3 = 0.f;
    #pragma unroll 4
    for (int k = 0; k < 128; ++k) {
        float w = Wq[(size_t)k * 1024 + c];
        a0 += x0[k] * w; a1 += x1[k] * w; a2 += x2[k] * w; a3 += x3[k] * w;
    }
    float bb = bq[c];
    q[(size_t)(r0 + 0) * 1024 + c] = a0 + bb;
    q[(size_t)(r0 + 1) * 1024 + c] = a1 + bb;
    q[(size_t)(r0 + 2) * 1024 + c] = a2 + bb;
    q[(size_t)(r0 + 3) * 1024 + c] = a3 + bb;
}

// ---------------- k3: QK[b,h,d] = q[b,h,:].WkT_h[:,d]; QBK[b,h] = q[b,h,:].bk_h ----------------
__global__ __launch_bounds__(256) void k_qk(
    const float* __restrict__ q, const float* __restrict__ WkT,
    const float* __restrict__ bk,
    float* __restrict__ QK, float* __restrict__ QBK)
{
    int bid = blockIdx.x, t = threadIdx.x;
    if (bid < 512) {
        int h = bid >> 6, rb = bid & 63;
        int b0 = rb * 8 + (t >> 7) * 4, c = t & 127;
        const float* A = q + (size_t)b0 * 1024 + h * 128;
        const float* W = WkT + (size_t)h * 16384 + c;
        float acc[4] = {0.f, 0.f, 0.f, 0.f};
        #pragma unroll 4
        for (int k = 0; k < 128; ++k) {
            float w = W[(size_t)k * 128];
            #pragma unroll
            for (int i = 0; i < 4; ++i) acc[i] += A[(size_t)i * 1024 + k] * w;
        }
        #pragma unroll
        for (int i = 0; i < 4; ++i) QK[(size_t)(b0 + i) * 1024 + h * 128 + c] = acc[i];
        return;
    }
    bid -= 512;                             // QBK: 64 pairs/block, 4 lanes per pair
    int pair = bid * 64 + (t >> 2), qd = t & 3;
    int bb = pair >> 3, h = pair & 7;
    const float* qp = q + (size_t)bb * 1024 + h * 128 + qd * 32;
    const float* bkp = bk + h * 128 + qd * 32;
    float acc = 0.f;
    #pragma unroll
    for (int k = 0; k < 32; ++k) acc += qp[k] * bkp[k];
    acc += __shfl_xor(acc, 1);
    acc += __shfl_xor(acc, 2);
    if (qd == 0) QBK[pair] = acc;
}

// ---------------- k4: per-molecule attention, X staged in LDS once ----------------
__global__ __launch_bounds__(256) void k_attn(
    const float* __restrict__ AF, const float* __restrict__ QK,
    const float* __restrict__ QBK, const int* __restrict__ offs,
    float* __restrict__ WX)
{
    int b = blockIdx.x, t = threadIdx.x;
    int o0 = offs[b], cnt = offs[b + 1] - o0;
    __shared__ float xs[128][132];          // +4 pad: 8 i-groups spread over all banks
    __shared__ float qs[8][132];
    __shared__ float s[8 * 136];            // [h][i], stride 136 -> <=2-way on writes
    __shared__ float mh[8], lh[8];
    const float4* af4 = (const float4*)(AF + (size_t)o0 * 128);
    for (int p = t; p < cnt * 32; p += 256) {   // stage X (coalesced, single global read)
        int i = p >> 5, d4 = p & 31;
        *(float4*)&xs[i][d4 * 4] = af4[p];
    }
    {                                       // stage QK row (4KB)
        int i = t >> 5, d4 = t & 31;
        *(float4*)&qs[i][d4 * 4] = ((const float4*)(QK + (size_t)b * 1024))[t];
    }
    __syncthreads();
    const float scale = 0.08838834764831843f;   // 1/sqrt(128)
    for (int p = t; p < cnt * 8; p += 256) {    // scores
        int i = p >> 3, h = p & 7;
        float acc = 0.f;
        #pragma unroll 8
        for (int d4 = 0; d4 < 32; ++d4) {
            float4 xv = *(const float4*)&xs[i][d4 * 4];
            float4 qv = *(const float4*)&qs[h][d4 * 4];
            acc += xv.x * qv.x + xv.y * qv.y + xv.z * qv.z + xv.w * qv.w;
        }
        s[h * 136 + i] = (acc + QBK[b * 8 + h]) * scale;
    }
    __syncthreads();
    {                                       // softmax stats: 32 lanes per head
        int h = t >> 5, lane = t & 31;
        float m = -1e30f;
        for (int i = lane; i < cnt; i += 32) m = fmaxf(m, s[h * 136 + i]);
        #pragma unroll
        for (int off = 16; off; off >>= 1) m = fmaxf(m, __shfl_xor(m, off));
        float l = 0.f;
        for (int i = lane; i < cnt; i += 32) l += __expf(s[h * 136 + i] - m);
        #pragma unroll
        for (int off = 16; off; off >>= 1) l += __shfl_xor(l, off);
        if (lane == 0) { mh[h] = m; lh[h] = 1.f / l; }
    }
    __syncthreads();
    for (int p = t; p < cnt * 8; p += 256) {
        int i = p >> 3, h = p & 7;
        s[h * 136 + i] = __expf(s[h * 136 + i] - mh[h]) * lh[h];
    }
    __syncthreads();
    {                                       // WX[h][:] = sum_i attn(i,h) x_i
        int hw = t >> 5, qq = t & 31;
        float4 a4 = {0.f, 0.f, 0.f, 0.f};
        for (int i = 0; i < cnt; ++i) {
            float sv = s[hw * 136 + i];
            float4 xv = *(const float4*)&xs[i][qq * 4];
            a4.x += sv * xv.x; a4.y += sv * xv.y; a4.z += sv * xv.z; a4.w += sv * xv.w;
        }
        ((float4*)(WX + (size_t)b * 1024 + hw * 128))[qq] = a4;
    }
}

// ---------------- batched row GEMV (unchanged pattern) ----------------
template<int NC, int KB, int RPT, bool RELU>
__global__ __launch_bounds__(256) void gemv_rows(
    const float* __restrict__ A, int lda,
    const float* __restrict__ W,
    const float* __restrict__ bias,
    float* __restrict__ out)
{
    constexpr int NCB = NC < 256 ? NC : 256;
    constexpr int TR  = 256 / NCB;
    constexpr int CCH = NC / NCB;
    int bx = blockIdx.x;
    int rblk = bx / CCH, cch = bx - rblk * CCH;
    int t = threadIdx.x;
    int c = (t & (NCB - 1)) + cch * NCB;
    int rr = (TR == 1) ? 0 : (t >> 7);
    int r0 = rblk * (TR * RPT) + rr * RPT;
    int koff = blockIdx.y * KB;
    const float* Ap = A + (size_t)r0 * lda + koff;
    const float* Wp = W + (size_t)koff * NC + c;
    float acc[RPT];
    #pragma unroll
    for (int i = 0; i < RPT; ++i) acc[i] = 0.f;
    #pragma unroll 4
    for (int k = 0; k < KB; ++k) {
        float w = Wp[(size_t)k * NC];
        #pragma unroll
        for (int i = 0; i < RPT; ++i) acc[i] += Ap[(size_t)i * lda + k] * w;
    }
    if (gridDim.y == 1) {
        float b = bias ? bias[c] : 0.f;
        #pragma unroll
        for (int i = 0; i < RPT; ++i) {
            float v = acc[i] + b;
            if (RELU) v = fmaxf(v, 0.f);
            out[(size_t)(r0 + i) * NC + c] = v;
        }
    } else {
        float* po = out + (size_t)blockIdx.y * BMOL * NC;
        #pragma unroll
        for (int i = 0; i < RPT; ++i) po[(size_t)(r0 + i) * NC + c] = acc[i];
    }
}

// ---------------- reduce partials + biases + residual + LayerNorm ----------------
template<bool GATHER>
__global__ __launch_bounds__(128) void k_ln(
    const float* __restrict__ part, int ks,
    const float* __restrict__ biasp, int nbp,
    const float* __restrict__ bias,
    const float* __restrict__ resid,
    const int* __restrict__ offs, const int* __restrict__ picked,
    const float* __restrict__ g, const float* __restrict__ be,
    float* __restrict__ out)
{
    int r = blockIdx.x, c = threadIdx.x;
    const float* rp = GATHER ? resid + (size_t)(offs[r] + picked[r]) * 128
                             : resid + (size_t)r * 128;
    float v = bias[c] + rp[c];
    for (int j = 0; j < nbp; ++j) v += biasp[j * 128 + c];
    for (int k = 0; k < ks; ++k) v += part[((size_t)k * BMOL + r) * 128 + c];
    float sm = v, sq = v * v;
    #pragma unroll
    for (int off = 32; off; off >>= 1) {
        sm += __shfl_xor(sm, off);
        sq += __shfl_xor(sq, off);
    }
    __shared__ float red[2][2];
    int wid = c >> 6;
    if ((c & 63) == 0) { red[wid][0] = sm; red[wid][1] = sq; }
    __syncthreads();
    float S = red[0][0] + red[1][0], Q = red[0][1] + red[1][1];
    float m = S * (1.f / 128.f);
    float var = Q * (1.f / 128.f) - m * m;
    out[(size_t)r * 128 + c] = (v - m) * rsqrtf(var + 1e-3f) * g[c] + be[c];
}

extern "C" void kernel_launch(void* const* d_in, const int* in_sizes, int n_in,
                              void* d_out, int out_size, void* d_ws, size_t ws_size,
                              hipStream_t stream) {
    const float* AF  = (const float*)d_in[0];
    const float* Wq  = (const float*)d_in[1];
    const float* bq  = (const float*)d_in[2];
    const float* Wk  = (const float*)d_in[3];
    const float* bk  = (const float*)d_in[4];
    const float* Wv  = (const float*)d_in[5];
    const float* bv  = (const float*)d_in[6];
    const float* Wo  = (const float*)d_in[7];
    const float* bo  = (const float*)d_in[8];
    const float* W1  = (const float*)d_in[9];
    const float* b1  = (const float*)d_in[10];
    const float* W2  = (const float*)d_in[11];
    const float* b2  = (const float*)d_in[12];
    const float* g1  = (const float*)d_in[13];
    const float* be1 = (const float*)d_in[14];
    const float* g2  = (const float*)d_in[15];
    const float* be2 = (const float*)d_in[16];
    const int* mol    = (const int*)d_in[17];
    const int* picked = (const int*)d_in[18];
    int N = in_sizes[0] / 128;
    int noff = (N + 255) / 256;

    char* ws = (char*)d_ws;
    int*   offs = (int*)ws;                       // 513 ints
    float* WkT  = (float*)(ws + 4096);            // [8][128][128] 512KB
    float* WVO  = (float*)(ws + 528384);          // [1024][128]   512KB
    float* bvoP = (float*)(ws + 1052672);         // [8][128]      4KB
    float* q    = (float*)(ws + 1056768);         // [512][1024]   2MB
    float* QK   = (float*)(ws + 3153920);         // [512][1024]   2MB
    float* QBK  = (float*)(ws + 5251072);         // [512][8]      16KB
    float* WX   = (float*)(ws + 5267456);         // [512][1024]   2MB
    float* P1   = (float*)(ws + 7364608);         // [4][512][128] 1MB
    float* H1   = (float*)(ws + 8413184);         // [512][128]    256KB
    float* MID  = (float*)(ws + 8675328);         // [512][512]    1MB
    float* P2   = (float*)(ws + 9723904);         // [4][512][128] 1MB

    k_prep<<<noff + 264, 256, 0, stream>>>(Wk, Wv, Wo, bv, mol, N, noff,
                                           offs, WkT, WVO, bvoP);
    k_q<<<512, 256, 0, stream>>>(AF, offs, picked, Wq, bq, q);
    k_qk<<<576, 256, 0, stream>>>(q, WkT, bk, QK, QBK);
    k_attn<<<BMOL, 256, 0, stream>>>(AF, QK, QBK, offs, WX);
    gemv_rows<128, 256, 4, false><<<dim3(64, 4), 256, 0, stream>>>(WX, 1024, WVO, nullptr, P1);
    k_ln<true><<<BMOL, 128, 0, stream>>>(P1, 4, bvoP, 8, bo, AF, offs, picked, g1, be1, H1);
    gemv_rows<512, 128, 4, true><<<dim3(256, 1), 256, 0, stream>>>(H1, 128, W1, b1, MID);
    gemv_rows<128, 128, 4, false><<<dim3(64, 4), 256, 0, stream>>>(MID, 512, W2, nullptr, P2);
    k_ln<false><<<BMOL, 128, 0, stream>>>(P2, 4, nullptr, 0, b2, H1, nullptr, nullptr, g2, be2, (float*)d_out);
}

// Round 3
// 107.532 us; speedup vs baseline: 1.3403x; 1.0356x over previous
//
#include <hip/hip_runtime.h>
#include <hip/hip_bf16.h>
#include <hip/hip_fp16.h>

// TransformerEncoderReadout: only the picked atom's output row is needed.
//   QK[b,h,:] = (xp_b . Wq_h + bq_h) . Wk_h^T      (q.bk drops out of softmax)
//   s(i,h)    = x_i . QK[b,h,:] / sqrt(128); softmax over i within molecule
//   WX[h,:]   = sum_i attn(i,h) x_i                 (softmax sums to 1 -> bv folds)
//   attn_out  = WX . WVO + (bv.Wo) + bo,  WVO_h = Wv_h . Wo_h
//   out_row   = LN2(h + FFN(h)),  h = LN1(xp + attn_out)
// 4 kernels: prep -> qk -> attn -> tail(everything row-local, fp16 weight streams).

#define BMOL 512

// ---------------- k1: offsets + WkT + WVO(fp16) + bvo partials + W1/W2 fp16 ----------------
__global__ __launch_bounds__(256) void k_prep(
    const float* __restrict__ Wk, const float* __restrict__ Wv,
    const float* __restrict__ Wo, const float* __restrict__ bv,
    const float* __restrict__ W1, const float* __restrict__ W2,
    const int* __restrict__ mol, int N, int noff,
    int* __restrict__ offs, float* __restrict__ WkT,
    __half* __restrict__ WVOh, float* __restrict__ bvoP,
    __half* __restrict__ W1h, __half* __restrict__ W2h)
{
    __shared__ float sh[32 * 33];
    int bid = blockIdx.x, t = threadIdx.x;
    if (bid < noff) {                       // segment offsets from sorted mol ids
        int i = bid * 256 + t;
        if (i < N) {
            if (i == 0) { offs[0] = 0; offs[BMOL] = N; }
            else if (mol[i] != mol[i - 1]) offs[mol[i]] = i;
        }
        return;
    }
    bid -= noff;
    if (bid < 128) {                        // WkT[h][kd][d] = Wk[d,h,kd], 32x32 LDS tiles
        int h = bid >> 4, tile = bid & 15;
        int td = tile >> 2, tk = tile & 3;
        int tx = t & 31, ty = t >> 5;
        #pragma unroll
        for (int rr = 0; rr < 4; ++rr) {
            int r = ty + rr * 8;
            sh[r * 33 + tx] = Wk[(size_t)(td * 32 + r) * 1024 + h * 128 + tk * 32 + tx];
        }
        __syncthreads();
        #pragma unroll
        for (int rr = 0; rr < 4; ++rr) {
            int c = ty + rr * 8;
            WkT[(size_t)h * 16384 + (tk * 32 + c) * 128 + td * 32 + tx] = sh[tx * 33 + c];
        }
        return;
    }
    bid -= 128;
    if (bid < 128) {                        // WVOh[(h*128+d)][d'] = sum_kd Wv[d,h,kd]*Wo[h,kd,d']
        int h = bid >> 4, rb = bid & 15;
        int rg = t >> 7, c = t & 127;
        int d0 = rb * 8 + rg * 4;
        const float* a = Wv + (size_t)d0 * 1024 + h * 128;
        const float* w = Wo + (size_t)h * 16384 + c;
        float acc[4] = {0.f, 0.f, 0.f, 0.f};
        #pragma unroll 4
        for (int kd = 0; kd < 128; ++kd) {
            float wv = w[(size_t)kd * 128];
            #pragma unroll
            for (int i = 0; i < 4; ++i) acc[i] += a[(size_t)i * 1024 + kd] * wv;
        }
        #pragma unroll
        for (int i = 0; i < 4; ++i)
            WVOh[(size_t)(h * 128 + d0 + i) * 128 + c] = __float2half_rn(acc[i]);
        return;
    }
    bid -= 128;
    if (bid < 8) {                          // bvoP[j][d'] = sum_{hk in j-th 128} bv[hk]*Wo[hk,d']
        int half = t >> 7, c = t & 127;
        float acc = 0.f;
        #pragma unroll 4
        for (int kk = 0; kk < 64; ++kk) {
            int k = bid * 128 + half * 64 + kk;
            acc += bv[k] * Wo[(size_t)k * 128 + c];
        }
        sh[half * 128 + c] = acc;
        __syncthreads();
        if (t < 128) bvoP[bid * 128 + t] = sh[t] + sh[128 + t];
        return;
    }
    bid -= 8;
    if (bid < 16) {                         // W1h: 65536 floats -> fp16
        __half2* dst = (__half2*)W1h;
        #pragma unroll
        for (int j = 0; j < 4; ++j) {
            int p = bid * 1024 + j * 256 + t;
            float4 x = ((const float4*)W1)[p];
            dst[p * 2]     = __floats2half2_rn(x.x, x.y);
            dst[p * 2 + 1] = __floats2half2_rn(x.z, x.w);
        }
        return;
    }
    bid -= 16;
    {                                       // W2h: 65536 floats -> fp16
        __half2* dst = (__half2*)W2h;
        #pragma unroll
        for (int j = 0; j < 4; ++j) {
            int p = bid * 1024 + j * 256 + t;
            float4 x = ((const float4*)W2)[p];
            dst[p * 2]     = __floats2half2_rn(x.x, x.y);
            dst[p * 2 + 1] = __floats2half2_rn(x.z, x.w);
        }
    }
}

// ---------------- k2: QK[b,h,:] = (xp.Wq_h + bq_h).WkT_h  (16 mols x 1 head / block) ----------
__global__ __launch_bounds__(512) void k_qk(
    const float* __restrict__ AF, const int* __restrict__ offs,
    const int* __restrict__ picked, const float* __restrict__ Wq,
    const float* __restrict__ bq, const float* __restrict__ WkT,
    float* __restrict__ QK)
{
    int h = blockIdx.x >> 5, m0 = (blockIdx.x & 31) * 16;
    int t = threadIdx.x;
    int c = t & 127, hh = t >> 7;           // hh in 0..3, wave-uniform
    int mb = hh * 4;
    __shared__ float xp[16][128];
    __shared__ float qs[16][128];
    {                                       // stage 16 picked rows (512 float4, 1 per thread)
        int m = t >> 5, d4 = t & 31;
        int row = offs[m0 + m] + picked[m0 + m];
        ((float4*)xp[m])[d4] = ((const float4*)(AF + (size_t)row * 128))[d4];
    }
    __syncthreads();
    {                                       // q[m][c] = xp[m,:].Wq[:,h,c] + bq
        const float* wq = Wq + h * 128 + c;
        float a0 = 0.f, a1 = 0.f, a2 = 0.f, a3 = 0.f;
        #pragma unroll 4
        for (int k = 0; k < 128; ++k) {
            float w = wq[(size_t)k * 1024];
            a0 += xp[mb][k] * w; a1 += xp[mb + 1][k] * w;
            a2 += xp[mb + 2][k] * w; a3 += xp[mb + 3][k] * w;
        }
        float bb = bq[h * 128 + c];
        qs[mb][c] = a0 + bb; qs[mb + 1][c] = a1 + bb;
        qs[mb + 2][c] = a2 + bb; qs[mb + 3][c] = a3 + bb;
    }
    __syncthreads();
    {                                       // QK[m][c] = q[m,:].WkT_h[:,c]
        const float* wk = WkT + (size_t)h * 16384 + c;
        float a0 = 0.f, a1 = 0.f, a2 = 0.f, a3 = 0.f;
        #pragma unroll 4
        for (int k = 0; k < 128; ++k) {
            float w = wk[(size_t)k * 128];
            a0 += qs[mb][k] * w; a1 += qs[mb + 1][k] * w;
            a2 += qs[mb + 2][k] * w; a3 += qs[mb + 3][k] * w;
        }
        QK[(size_t)(m0 + mb + 0) * 1024 + h * 128 + c] = a0;
        QK[(size_t)(m0 + mb + 1) * 1024 + h * 128 + c] = a1;
        QK[(size_t)(m0 + mb + 2) * 1024 + h * 128 + c] = a2;
        QK[(size_t)(m0 + mb + 3) * 1024 + h * 128 + c] = a3;
    }
}

// ---------------- k3: per-molecule attention, X staged in LDS once ----------------
__global__ __launch_bounds__(256) void k_attn(
    const float* __restrict__ AF, const float* __restrict__ QK,
    const int* __restrict__ offs, float* __restrict__ WX)
{
    int b = blockIdx.x, t = threadIdx.x;
    int o0 = offs[b], cnt = offs[b + 1] - o0;
    __shared__ float xs[128][132];          // +4 pad spreads 8 i-group reads over banks
    __shared__ float qs[8][132];
    __shared__ float s[8 * 136];            // [h][i]
    __shared__ float mh[8], lh[8];
    const float4* af4 = (const float4*)(AF + (size_t)o0 * 128);
    for (int p = t; p < cnt * 32; p += 256) {   // stage X once (coalesced)
        int i = p >> 5, d4 = p & 31;
        *(float4*)&xs[i][d4 * 4] = af4[p];
    }
    {                                       // stage QK row (4KB)
        int i = t >> 5, d4 = t & 31;
        *(float4*)&qs[i][d4 * 4] = ((const float4*)(QK + (size_t)b * 1024))[t];
    }
    __syncthreads();
    const float scale = 0.08838834764831843f;   // 1/sqrt(128)
    for (int p = t; p < cnt * 8; p += 256) {    // scores
        int i = p >> 3, h = p & 7;
        float acc = 0.f;
        #pragma unroll 8
        for (int d4 = 0; d4 < 32; ++d4) {
            float4 xv = *(const float4*)&xs[i][d4 * 4];
            float4 qv = *(const float4*)&qs[h][d4 * 4];
            acc += xv.x * qv.x + xv.y * qv.y + xv.z * qv.z + xv.w * qv.w;
        }
        s[h * 136 + i] = acc * scale;
    }
    __syncthreads();
    {                                       // softmax stats: 32 lanes per head
        int h = t >> 5, lane = t & 31;
        float m = -1e30f;
        for (int i = lane; i < cnt; i += 32) m = fmaxf(m, s[h * 136 + i]);
        #pragma unroll
        for (int off = 16; off; off >>= 1) m = fmaxf(m, __shfl_xor(m, off));
        float l = 0.f;
        for (int i = lane; i < cnt; i += 32) l += __expf(s[h * 136 + i] - m);
        #pragma unroll
        for (int off = 16; off; off >>= 1) l += __shfl_xor(l, off);
        if (lane == 0) { mh[h] = m; lh[h] = 1.f / l; }
    }
    __syncthreads();
    for (int p = t; p < cnt * 8; p += 256) {
        int i = p >> 3, h = p & 7;
        s[h * 136 + i] = __expf(s[h * 136 + i] - mh[h]) * lh[h];
    }
    __syncthreads();
    {                                       // WX[h][:] = sum_i attn(i,h) x_i
        int hw = t >> 5, qq = t & 31;
        float4 a4 = {0.f, 0.f, 0.f, 0.f};
        for (int i = 0; i < cnt; ++i) {
            float sv = s[hw * 136 + i];
            float4 xv = *(const float4*)&xs[i][qq * 4];
            a4.x += sv * xv.x; a4.y += sv * xv.y; a4.z += sv * xv.z; a4.w += sv * xv.w;
        }
        ((float4*)(WX + (size_t)b * 1024 + hw * 128))[qq] = a4;
    }
}

// ---------------- k4: fused tail, 4 molecules/block ----------------
// attn_out gemv (K=1024, fp16 W) + biases + residual + LN1 -> FFN1 relu -> FFN2 + LN2 -> out
__global__ __launch_bounds__(256) void k_tail(
    const float* __restrict__ WX, const __half* __restrict__ WVOh,
    const float* __restrict__ bvoP, const float* __restrict__ bo,
    const float* __restrict__ AF, const int* __restrict__ offs,
    const int* __restrict__ picked,
    const float* __restrict__ g1, const float* __restrict__ be1,
    const __half* __restrict__ W1h, const float* __restrict__ b1,
    const __half* __restrict__ W2h, const float* __restrict__ b2,
    const float* __restrict__ g2, const float* __restrict__ be2,
    float* __restrict__ out)
{
    int r0 = blockIdx.x * 4, t = threadIdx.x;
    int c = t & 127, rg = t >> 7;           // rg: rows rg*2 + {0,1}
    int wv = (t >> 6) & 1;                  // which c-half wave
    __shared__ float h1s[4][128];
    __shared__ float mids[4][512];
    __shared__ float red[2][2][4];
    float v0, v1;
    {   // ---- phase A: attn_out rows ----
        const __half* wp = WVOh + c;
        const float* wxa = WX + (size_t)(r0 + rg * 2) * 1024;
        const float* wxb = wxa + 1024;
        float a0 = 0.f, a1 = 0.f, a2 = 0.f, a3 = 0.f;
        float b0 = 0.f, b1v = 0.f, b2v = 0.f, b3 = 0.f;
        for (int k = 0; k < 1024; k += 4) {
            float w0 = __half2float(wp[(size_t)(k + 0) * 128]);
            float w1 = __half2float(wp[(size_t)(k + 1) * 128]);
            float w2 = __half2float(wp[(size_t)(k + 2) * 128]);
            float w3 = __half2float(wp[(size_t)(k + 3) * 128]);
            a0 += wxa[k] * w0;     a1 += wxa[k + 1] * w1;
            a2 += wxa[k + 2] * w2; a3 += wxa[k + 3] * w3;
            b0 += wxb[k] * w0;     b1v += wxb[k + 1] * w1;
            b2v += wxb[k + 2] * w2; b3 += wxb[k + 3] * w3;
        }
        float bias1 = bo[c];
        #pragma unroll
        for (int j = 0; j < 8; ++j) bias1 += bvoP[j * 128 + c];
        int ra = r0 + rg * 2, rb = ra + 1;
        v0 = a0 + a1 + a2 + a3 + bias1 + AF[(size_t)(offs[ra] + picked[ra]) * 128 + c];
        v1 = b0 + b1v + b2v + b3 + bias1 + AF[(size_t)(offs[rb] + picked[rb]) * 128 + c];
    }
    {   // ---- LN1 over c (2 waves per row-group) ----
        float s0 = v0, q0 = v0 * v0, s1 = v1, q1 = v1 * v1;
        #pragma unroll
        for (int off = 32; off; off >>= 1) {
            s0 += __shfl_xor(s0, off); q0 += __shfl_xor(q0, off);
            s1 += __shfl_xor(s1, off); q1 += __shfl_xor(q1, off);
        }
        if ((t & 63) == 0) { red[rg][wv][0] = s0; red[rg][wv][1] = q0; red[rg][wv][2] = s1; red[rg][wv][3] = q1; }
        __syncthreads();
        float S0 = red[rg][0][0] + red[rg][1][0], Q0 = red[rg][0][1] + red[rg][1][1];
        float S1 = red[rg][0][2] + red[rg][1][2], Q1 = red[rg][0][3] + red[rg][1][3];
        float m0 = S0 * (1.f / 128.f), va0 = Q0 * (1.f / 128.f) - m0 * m0;
        float m1 = S1 * (1.f / 128.f), va1 = Q1 * (1.f / 128.f) - m1 * m1;
        h1s[rg * 2][c]     = (v0 - m0) * rsqrtf(va0 + 1e-3f) * g1[c] + be1[c];
        h1s[rg * 2 + 1][c] = (v1 - m1) * rsqrtf(va1 + 1e-3f) * g1[c] + be1[c];
    }
    __syncthreads();
    {   // ---- phase B: mid = relu(h1.W1 + b1), cols t and t+256 ----
        const __half* wp = W1h + t;
        float acc[4][2] = {{0.f,0.f},{0.f,0.f},{0.f,0.f},{0.f,0.f}};
        #pragma unroll 2
        for (int k = 0; k < 128; ++k) {
            float wa = __half2float(wp[(size_t)k * 512]);
            float wb = __half2float(wp[(size_t)k * 512 + 256]);
            #pragma unroll
            for (int r = 0; r < 4; ++r) {
                float h = h1s[r][k];
                acc[r][0] += h * wa; acc[r][1] += h * wb;
            }
        }
        float ba = b1[t], bb = b1[t + 256];
        #pragma unroll
        for (int r = 0; r < 4; ++r) {
            mids[r][t]       = fmaxf(acc[r][0] + ba, 0.f);
            mids[r][t + 256] = fmaxf(acc[r][1] + bb, 0.f);
        }
    }
    __syncthreads();
    {   // ---- phase C: out = LN2(h1 + mid.W2 + b2) ----
        const __half* wp = W2h + c;
        const float* ma = mids[rg * 2];
        const float* mb = mids[rg * 2 + 1];
        float a0 = 0.f, a1 = 0.f, a2 = 0.f, a3 = 0.f;
        float b0 = 0.f, b1v = 0.f, b2v = 0.f, b3 = 0.f;
        for (int k = 0; k < 512; k += 4) {
            float w0 = __half2float(wp[(size_t)(k + 0) * 128]);
            float w1 = __half2float(wp[(size_t)(k + 1) * 128]);
            float w2 = __half2float(wp[(size_t)(k + 2) * 128]);
            float w3 = __half2float(wp[(size_t)(k + 3) * 128]);
            a0 += ma[k] * w0;     a1 += ma[k + 1] * w1;
            a2 += ma[k + 2] * w2; a3 += ma[k + 3] * w3;
            b0 += mb[k] * w0;     b1v += mb[k + 1] * w1;
            b2v += mb[k + 2] * w2; b3 += mb[k + 3] * w3;
        }
        v0 = a0 + a1 + a2 + a3 + b2[c] + h1s[rg * 2][c];
        v1 = b0 + b1v + b2v + b3 + b2[c] + h1s[rg * 2 + 1][c];
        float s0 = v0, q0 = v0 * v0, s1 = v1, q1 = v1 * v1;
        #pragma unroll
        for (int off = 32; off; off >>= 1) {
            s0 += __shfl_xor(s0, off); q0 += __shfl_xor(q0, off);
            s1 += __shfl_xor(s1, off); q1 += __shfl_xor(q1, off);
        }
        if ((t & 63) == 0) { red[rg][wv][0] = s0; red[rg][wv][1] = q0; red[rg][wv][2] = s1; red[rg][wv][3] = q1; }
        __syncthreads();
        float S0 = red[rg][0][0] + red[rg][1][0], Q0 = red[rg][0][1] + red[rg][1][1];
        float S1 = red[rg][0][2] + red[rg][1][2], Q1 = red[rg][0][3] + red[rg][1][3];
        float m0 = S0 * (1.f / 128.f), va0 = Q0 * (1.f / 128.f) - m0 * m0;
        float m1 = S1 * (1.f / 128.f), va1 = Q1 * (1.f / 128.f) - m1 * m1;
        out[(size_t)(r0 + rg * 2) * 128 + c]     = (v0 - m0) * rsqrtf(va0 + 1e-3f) * g2[c] + be2[c];
        out[(size_t)(r0 + rg * 2 + 1) * 128 + c] = (v1 - m1) * rsqrtf(va1 + 1e-3f) * g2[c] + be2[c];
    }
}

extern "C" void kernel_launch(void* const* d_in, const int* in_sizes, int n_in,
                              void* d_out, int out_size, void* d_ws, size_t ws_size,
                              hipStream_t stream) {
    const float* AF  = (const float*)d_in[0];
    const float* Wq  = (const float*)d_in[1];
    const float* bq  = (const float*)d_in[2];
    const float* Wk  = (const float*)d_in[3];
    const float* Wv  = (const float*)d_in[5];
    const float* bv  = (const float*)d_in[6];
    const float* Wo  = (const float*)d_in[7];
    const float* bo  = (const float*)d_in[8];
    const float* W1  = (const float*)d_in[9];
    const float* b1  = (const float*)d_in[10];
    const float* W2  = (const float*)d_in[11];
    const float* b2  = (const float*)d_in[12];
    const float* g1  = (const float*)d_in[13];
    const float* be1 = (const float*)d_in[14];
    const float* g2  = (const float*)d_in[15];
    const float* be2 = (const float*)d_in[16];
    const int* mol    = (const int*)d_in[17];
    const int* picked = (const int*)d_in[18];
    int N = in_sizes[0] / 128;
    int noff = (N + 255) / 256;

    char* ws = (char*)d_ws;
    int*    offs = (int*)ws;                      // 513 ints
    float*  WkT  = (float*)(ws + 4096);           // [8][128][128] 512KB
    __half* WVOh = (__half*)(ws + 528384);        // [1024][128]   256KB
    float*  bvoP = (float*)(ws + 790528);         // [8][128]      4KB
    __half* W1h  = (__half*)(ws + 794624);        // [128][512]    128KB
    __half* W2h  = (__half*)(ws + 925696);        // [512][128]    128KB
    float*  QK   = (float*)(ws + 1056768);        // [512][1024]   2MB
    float*  WX   = (float*)(ws + 3153920);        // [512][1024]   2MB

    k_prep<<<noff + 296, 256, 0, stream>>>(Wk, Wv, Wo, bv, W1, W2, mol, N, noff,
                                           offs, WkT, WVOh, bvoP, W1h, W2h);
    k_qk<<<256, 512, 0, stream>>>(AF, offs, picked, Wq, bq, WkT, QK);
    k_attn<<<BMOL, 256, 0, stream>>>(AF, QK, offs, WX);
    k_tail<<<128, 256, 0, stream>>>(WX, WVOh, bvoP, bo, AF, offs, picked,
                                    g1, be1, W1h, b1, W2h, b2, g2, be2, (float*)d_out);
}

// Round 4
// 70.223 us; speedup vs baseline: 2.0523x; 1.5313x over previous
//
#include <hip/hip_runtime.h>
#include <hip/hip_bf16.h>
#include <hip/hip_fp16.h>

// TransformerEncoderReadout: only the picked atom's output row is needed.
//   QK[b,h,:] = (xp_b . Wq_h + bq_h) . Wk_h^T      (q.bk drops out of softmax)
//   s(i,h)    = x_i . QK[b,h,:] / sqrt(128); softmax over i within molecule
//   WX[h,:]   = sum_i attn(i,h) x_i                 (softmax sums to 1 -> bv folds)
//   attn_out  = WX . WVO + (bv.Wo) + bo,  WVO_h = Wv_h . Wo_h
//   out_row   = LN2(h + FFN(h)),  h = LN1(xp + attn_out)
// 3 kernels: prep -> qk -> fused attn+tail (one block per molecule).
// Weights for the tail are packed fp16 [K/8][C][8] so each thread's K-run is
// one 16B load, coalesced across threads (fixes R3's 55us latency-bound tail).

#define BMOL 512

// ---------------- k1: offsets + WkT + packed WVO/W1/W2 + bvo partials ----------------
__global__ __launch_bounds__(256) void k_prep(
    const float* __restrict__ Wk, const float* __restrict__ Wv,
    const float* __restrict__ Wo, const float* __restrict__ bv,
    const float* __restrict__ W1, const float* __restrict__ W2,
    const int* __restrict__ mol, int N, int noff,
    int* __restrict__ offs, float* __restrict__ WkT,
    __half* __restrict__ WVOp, float* __restrict__ bvoP,
    __half* __restrict__ W1p, __half* __restrict__ W2p)
{
    __shared__ float sh[32 * 33];
    int bid = blockIdx.x, t = threadIdx.x;
    if (bid < noff) {                       // segment offsets from sorted mol ids
        int i = bid * 256 + t;
        if (i < N) {
            if (i == 0) { offs[0] = 0; offs[BMOL] = N; }
            else if (mol[i] != mol[i - 1]) offs[mol[i]] = i;
        }
        return;
    }
    bid -= noff;
    if (bid < 128) {                        // WkT[h][kd][d] = Wk[d,h,kd], 32x32 LDS tiles
        int h = bid >> 4, tile = bid & 15;
        int td = tile >> 2, tk = tile & 3;
        int tx = t & 31, ty = t >> 5;
        #pragma unroll
        for (int rr = 0; rr < 4; ++rr) {
            int r = ty + rr * 8;
            sh[r * 33 + tx] = Wk[(size_t)(td * 32 + r) * 1024 + h * 128 + tk * 32 + tx];
        }
        __syncthreads();
        #pragma unroll
        for (int rr = 0; rr < 4; ++rr) {
            int c = ty + rr * 8;
            WkT[(size_t)h * 16384 + (tk * 32 + c) * 128 + td * 32 + tx] = sh[tx * 33 + c];
        }
        return;
    }
    bid -= 128;
    if (bid < 128) {                        // WVOp[(k>>3)][c][k&7] = sum_kd Wv[d,h,kd]*Wo[h,kd,c], k=h*128+d
        int h = bid >> 4, rb = bid & 15;
        int rg = t >> 7, c = t & 127;
        int d0 = rb * 8 + rg * 4;
        const float* a = Wv + (size_t)d0 * 1024 + h * 128;
        const float* w = Wo + (size_t)h * 16384 + c;
        float acc[4] = {0.f, 0.f, 0.f, 0.f};
        #pragma unroll 4
        for (int kd = 0; kd < 128; ++kd) {
            float wv = w[(size_t)kd * 128];
            #pragma unroll
            for (int i = 0; i < 4; ++i) acc[i] += a[(size_t)i * 1024 + kd] * wv;
        }
        // k = h*128 + d0 + i; k>>3 = h*16+rb; k&7 = rg*4+i
        __half2 p0 = __floats2half2_rn(acc[0], acc[1]);
        __half2 p1 = __floats2half2_rn(acc[2], acc[3]);
        __half2* dst = (__half2*)(WVOp + (size_t)(h * 16 + rb) * 1024 + c * 8 + rg * 4);
        dst[0] = p0; dst[1] = p1;
        return;
    }
    bid -= 128;
    if (bid < 8) {                          // bvoP[j][c] = sum_{hk in j-th 128} bv[hk]*Wo[hk,c]
        int half = t >> 7, c = t & 127;
        float acc = 0.f;
        #pragma unroll 4
        for (int kk = 0; kk < 64; ++kk) {
            int k = bid * 128 + half * 64 + kk;
            acc += bv[k] * Wo[(size_t)k * 128 + c];
        }
        sh[half * 128 + c] = acc;
        __syncthreads();
        if (t < 128) bvoP[bid * 128 + t] = sh[t] + sh[128 + t];
        return;
    }
    bid -= 8;
    if (bid < 32) {                         // W1p[(k>>3)][f][k&7], K=128, F=512
        int g = bid * 256 + t;              // 8192
        int kg = g >> 9, f = g & 511;
        __half2 p[4];
        #pragma unroll
        for (int j = 0; j < 4; ++j) {
            float a = W1[(size_t)(kg * 8 + 2 * j) * 512 + f];
            float b = W1[(size_t)(kg * 8 + 2 * j + 1) * 512 + f];
            p[j] = __floats2half2_rn(a, b);
        }
        *(float4*)(W1p + (size_t)kg * 4096 + f * 8) = *(float4*)p;
        return;
    }
    bid -= 32;
    {                                       // W2p[(f>>3)][c][f&7], K=512, C=128
        int g = bid * 256 + t;              // 8192
        int fg = g >> 7, c = g & 127;
        __half2 p[4];
        #pragma unroll
        for (int j = 0; j < 4; ++j) {
            float a = W2[(size_t)(fg * 8 + 2 * j) * 128 + c];
            float b = W2[(size_t)(fg * 8 + 2 * j + 1) * 128 + c];
            p[j] = __floats2half2_rn(a, b);
        }
        *(float4*)(W2p + (size_t)fg * 1024 + c * 8) = *(float4*)p;
    }
}

// ---------------- k2: QK[b,h,:] = (xp.Wq_h + bq_h).WkT_h  (16 mols x 1 head / block) --------
__global__ __launch_bounds__(512) void k_qk(
    const float* __restrict__ AF, const int* __restrict__ offs,
    const int* __restrict__ picked, const float* __restrict__ Wq,
    const float* __restrict__ bq, const float* __restrict__ WkT,
    float* __restrict__ QK)
{
    int h = blockIdx.x >> 5, m0 = (blockIdx.x & 31) * 16;
    int t = threadIdx.x;
    int c = t & 127, hh = t >> 7;
    int mb = hh * 4;
    __shared__ float xp[16][128];
    __shared__ float qs[16][128];
    {
        int m = t >> 5, d4 = t & 31;
        int row = offs[m0 + m] + picked[m0 + m];
        ((float4*)xp[m])[d4] = ((const float4*)(AF + (size_t)row * 128))[d4];
    }
    __syncthreads();
    {
        const float* wq = Wq + h * 128 + c;
        float a0 = 0.f, a1 = 0.f, a2 = 0.f, a3 = 0.f;
        #pragma unroll 4
        for (int k = 0; k < 128; ++k) {
            float w = wq[(size_t)k * 1024];
            a0 += xp[mb][k] * w; a1 += xp[mb + 1][k] * w;
            a2 += xp[mb + 2][k] * w; a3 += xp[mb + 3][k] * w;
        }
        float bb = bq[h * 128 + c];
        qs[mb][c] = a0 + bb; qs[mb + 1][c] = a1 + bb;
        qs[mb + 2][c] = a2 + bb; qs[mb + 3][c] = a3 + bb;
    }
    __syncthreads();
    {
        const float* wk = WkT + (size_t)h * 16384 + c;
        float a0 = 0.f, a1 = 0.f, a2 = 0.f, a3 = 0.f;
        #pragma unroll 4
        for (int k = 0; k < 128; ++k) {
            float w = wk[(size_t)k * 128];
            a0 += qs[mb][k] * w; a1 += qs[mb + 1][k] * w;
            a2 += qs[mb + 2][k] * w; a3 += qs[mb + 3][k] * w;
        }
        QK[(size_t)(m0 + mb + 0) * 1024 + h * 128 + c] = a0;
        QK[(size_t)(m0 + mb + 1) * 1024 + h * 128 + c] = a1;
        QK[(size_t)(m0 + mb + 2) * 1024 + h * 128 + c] = a2;
        QK[(size_t)(m0 + mb + 3) * 1024 + h * 128 + c] = a3;
    }
}

// ---------------- k3: fused attention + tail, one block per molecule ----------------
__global__ __launch_bounds__(256) void k_attn_tail(
    const float* __restrict__ AF, const float* __restrict__ QK,
    const int* __restrict__ offs, const int* __restrict__ picked,
    const __half* __restrict__ WVOp, const float* __restrict__ bvoP,
    const float* __restrict__ bo,
    const float* __restrict__ g1, const float* __restrict__ be1,
    const __half* __restrict__ W1p, const float* __restrict__ b1,
    const __half* __restrict__ W2p, const float* __restrict__ b2,
    const float* __restrict__ g2, const float* __restrict__ be2,
    float* __restrict__ out)
{
    int b = blockIdx.x, t = threadIdx.x;
    int o0 = offs[b], cnt = offs[b + 1] - o0;
    __shared__ __half xs[128][136];         // fp16 X; row = 272B = 17x16B (aligned, bank-spread)
    __shared__ float qs[8][132];
    __shared__ float s[8 * 136];
    __shared__ float mh[8], lh[8];
    __shared__ float ws[1024];              // WX (attention-weighted X)
    __shared__ float h1raw[128], h1n[128], ms[512];

    const float4* af4 = (const float4*)(AF + (size_t)o0 * 128);
    for (int p = t; p < cnt * 32; p += 256) {   // stage X once, f32->f16
        int i = p >> 5, d4 = p & 31;
        float4 v = af4[p];
        float2 st;
        ((__half2*)&st)[0] = __floats2half2_rn(v.x, v.y);
        ((__half2*)&st)[1] = __floats2half2_rn(v.z, v.w);
        *(float2*)(&xs[i][d4 * 4]) = st;
    }
    {                                       // stage QK row (4KB)
        int i = t >> 5, d4 = t & 31;
        *(float4*)(&qs[i][d4 * 4]) = ((const float4*)(QK + (size_t)b * 1024))[t];
    }
    __syncthreads();
    const float scale = 0.08838834764831843f;   // 1/sqrt(128)
    for (int p = t; p < cnt * 8; p += 256) {    // scores
        int i = p >> 3, h = p & 7;
        float acc = 0.f;
        #pragma unroll 8
        for (int dq = 0; dq < 16; ++dq) {
            float4 xraw = ((const float4*)xs[i])[dq];
            const __half2* xh = (const __half2*)&xraw;
            float4 q0 = ((const float4*)qs[h])[dq * 2];
            float4 q1 = ((const float4*)qs[h])[dq * 2 + 1];
            float2 x0 = __half22float2(xh[0]), x1 = __half22float2(xh[1]);
            float2 x2 = __half22float2(xh[2]), x3 = __half22float2(xh[3]);
            acc += x0.x * q0.x + x0.y * q0.y + x1.x * q0.z + x1.y * q0.w
                 + x2.x * q1.x + x2.y * q1.y + x3.x * q1.z + x3.y * q1.w;
        }
        s[h * 136 + i] = acc * scale;
    }
    __syncthreads();
    {                                       // softmax stats: 32 lanes per head
        int h = t >> 5, lane = t & 31;
        float m = -1e30f;
        for (int i = lane; i < cnt; i += 32) m = fmaxf(m, s[h * 136 + i]);
        #pragma unroll
        for (int off = 16; off; off >>= 1) m = fmaxf(m, __shfl_xor(m, off));
        float l = 0.f;
        for (int i = lane; i < cnt; i += 32) l += __expf(s[h * 136 + i] - m);
        #pragma unroll
        for (int off = 16; off; off >>= 1) l += __shfl_xor(l, off);
        if (lane == 0) { mh[h] = m; lh[h] = 1.f / l; }
    }
    __syncthreads();
    for (int p = t; p < cnt * 8; p += 256) {
        int i = p >> 3, h = p & 7;
        s[h * 136 + i] = __expf(s[h * 136 + i] - mh[h]) * lh[h];
    }
    __syncthreads();
    {                                       // WX[h][:] = sum_i attn(i,h) x_i -> LDS ws
        int hw = t >> 5, qq = t & 31;
        float4 a4 = {0.f, 0.f, 0.f, 0.f};
        for (int i = 0; i < cnt; ++i) {
            float sv = s[hw * 136 + i];
            float2 xraw = *(const float2*)(&xs[i][qq * 4]);
            const __half2* xh = (const __half2*)&xraw;
            float2 x0 = __half22float2(xh[0]), x1 = __half22float2(xh[1]);
            a4.x += sv * x0.x; a4.y += sv * x0.y; a4.z += sv * x1.x; a4.w += sv * x1.y;
        }
        *(float4*)(&ws[hw * 128 + qq * 4]) = a4;
    }
    __syncthreads();
    // ---- tail phase A: attn_out[c] = ws . WVO[:,c], K=1024 split over lane pairs ----
    int c = t >> 1, kh = t & 1;
    {
        const __half* wp = WVOp + (size_t)(kh * 64) * 1024 + c * 8;
        float acc = 0.f;
        #pragma unroll 8
        for (int g = 0; g < 64; ++g) {
            float4 raw = *(const float4*)(wp + (size_t)g * 1024);
            const __half2* hp = (const __half2*)&raw;
            const float* wk = ws + kh * 512 + g * 8;
            float2 w0 = __half22float2(hp[0]), w1 = __half22float2(hp[1]);
            float2 w2 = __half22float2(hp[2]), w3 = __half22float2(hp[3]);
            acc += wk[0] * w0.x + wk[1] * w0.y + wk[2] * w1.x + wk[3] * w1.y
                 + wk[4] * w2.x + wk[5] * w2.y + wk[6] * w3.x + wk[7] * w3.y;
        }
        acc += __shfl_xor(acc, 1);
        if (!kh) {
            float bias = bo[c];
            #pragma unroll
            for (int j = 0; j < 8; ++j) bias += bvoP[j * 128 + c];
            int row = o0 + picked[b];
            h1raw[c] = acc + bias + AF[(size_t)row * 128 + c];
        }
    }
    __syncthreads();
    {   // LN1 (redundant per wave)
        int l = t & 63;
        float a = h1raw[l], bb = h1raw[l + 64];
        float sm = a + bb, sq = a * a + bb * bb;
        #pragma unroll
        for (int off = 32; off; off >>= 1) { sm += __shfl_xor(sm, off); sq += __shfl_xor(sq, off); }
        float m = sm * (1.f / 128.f), var = sq * (1.f / 128.f) - m * m;
        float rs = rsqrtf(var + 1e-3f);
        if (t < 128) h1n[t] = (h1raw[t] - m) * rs * g1[t] + be1[t];
    }
    __syncthreads();
    {   // phase B: mid[f] = relu(h1n.W1[:,f] + b1), f = t and t+256
        float acc0 = 0.f, acc1 = 0.f;
        const __half* wp0 = W1p + t * 8;
        const __half* wp1 = W1p + (t + 256) * 8;
        #pragma unroll 8
        for (int g = 0; g < 16; ++g) {
            float4 r0 = *(const float4*)(wp0 + (size_t)g * 4096);
            float4 r1 = *(const float4*)(wp1 + (size_t)g * 4096);
            const float* hk = h1n + g * 8;
            const __half2* a0 = (const __half2*)&r0;
            const __half2* a1 = (const __half2*)&r1;
            #pragma unroll
            for (int j = 0; j < 4; ++j) {
                float2 u = __half22float2(a0[j]), v = __half22float2(a1[j]);
                acc0 += hk[2 * j] * u.x + hk[2 * j + 1] * u.y;
                acc1 += hk[2 * j] * v.x + hk[2 * j + 1] * v.y;
            }
        }
        ms[t] = fmaxf(acc0 + b1[t], 0.f);
        ms[t + 256] = fmaxf(acc1 + b1[t + 256], 0.f);
    }
    __syncthreads();
    {   // phase C: outraw[c] = ms . W2[:,c] + b2 + h1n, K=512 split over lane pairs
        const __half* wp = W2p + (size_t)(kh * 32) * 1024 + c * 8;
        float acc = 0.f;
        #pragma unroll 8
        for (int g = 0; g < 32; ++g) {
            float4 raw = *(const float4*)(wp + (size_t)g * 1024);
            const __half2* hp = (const __half2*)&raw;
            const float* mk = ms + kh * 256 + g * 8;
            float2 w0 = __half22float2(hp[0]), w1 = __half22float2(hp[1]);
            float2 w2 = __half22float2(hp[2]), w3 = __half22float2(hp[3]);
            acc += mk[0] * w0.x + mk[1] * w0.y + mk[2] * w1.x + mk[3] * w1.y
                 + mk[4] * w2.x + mk[5] * w2.y + mk[6] * w3.x + mk[7] * w3.y;
        }
        acc += __shfl_xor(acc, 1);
        if (!kh) h1raw[c] = acc + b2[c] + h1n[c];
    }
    __syncthreads();
    {   // LN2 (redundant per wave) -> global out
        int l = t & 63;
        float a = h1raw[l], bb = h1raw[l + 64];
        float sm = a + bb, sq = a * a + bb * bb;
        #pragma unroll
        for (int off = 32; off; off >>= 1) { sm += __shfl_xor(sm, off); sq += __shfl_xor(sq, off); }
        float m = sm * (1.f / 128.f), var = sq * (1.f / 128.f) - m * m;
        float rs = rsqrtf(var + 1e-3f);
        if (t < 128) out[(size_t)b * 128 + t] = (h1raw[t] - m) * rs * g2[t] + be2[t];
    }
}

extern "C" void kernel_launch(void* const* d_in, const int* in_sizes, int n_in,
                              void* d_out, int out_size, void* d_ws, size_t ws_size,
                              hipStream_t stream) {
    const float* AF  = (const float*)d_in[0];
    const float* Wq  = (const float*)d_in[1];
    const float* bq  = (const float*)d_in[2];
    const float* Wk  = (const float*)d_in[3];
    const float* Wv  = (const float*)d_in[5];
    const float* bv  = (const float*)d_in[6];
    const float* Wo  = (const float*)d_in[7];
    const float* bo  = (const float*)d_in[8];
    const float* W1  = (const float*)d_in[9];
    const float* b1  = (const float*)d_in[10];
    const float* W2  = (const float*)d_in[11];
    const float* b2  = (const float*)d_in[12];
    const float* g1  = (const float*)d_in[13];
    const float* be1 = (const float*)d_in[14];
    const float* g2  = (const float*)d_in[15];
    const float* be2 = (const float*)d_in[16];
    const int* mol    = (const int*)d_in[17];
    const int* picked = (const int*)d_in[18];
    int N = in_sizes[0] / 128;
    int noff = (N + 255) / 256;

    char* ws = (char*)d_ws;
    int*    offs = (int*)ws;                      // 513 ints
    float*  WkT  = (float*)(ws + 4096);           // [8][128][128] 512KB
    __half* WVOp = (__half*)(ws + 528384);        // packed [128][128][8] 256KB
    float*  bvoP = (float*)(ws + 790528);         // [8][128] 4KB
    __half* W1p  = (__half*)(ws + 794624);        // packed [16][512][8] 128KB
    __half* W2p  = (__half*)(ws + 925696);        // packed [64][128][8] 128KB
    float*  QK   = (float*)(ws + 1056768);        // [512][1024] 2MB

    k_prep<<<noff + 328, 256, 0, stream>>>(Wk, Wv, Wo, bv, W1, W2, mol, N, noff,
                                           offs, WkT, WVOp, bvoP, W1p, W2p);
    k_qk<<<256, 512, 0, stream>>>(AF, offs, picked, Wq, bq, WkT, QK);
    k_attn_tail<<<BMOL, 256, 0, stream>>>(AF, QK, offs, picked, WVOp, bvoP, bo,
                                          g1, be1, W1p, b1, W2p, b2, g2, be2,
                                          (float*)d_out);
}

// Round 5
// 59.714 us; speedup vs baseline: 2.4135x; 1.1760x over previous
//
#include <hip/hip_runtime.h>
#include <hip/hip_bf16.h>
#include <hip/hip_fp16.h>

// TransformerEncoderReadout: only the picked atom's output row is needed.
//   QK[b,h,:] = (xp_b . Wq_h + bq_h) . Wk_h^T      (q.bk drops out of softmax)
//   s(i,h)    = x_i . QK[b,h,:] / sqrt(128); softmax over i within molecule
//   WX[h,:]   = sum_i attn(i,h) x_i                 (softmax sums to 1 -> bv folds)
//   attn_out  = WX . WVO + (bv.Wo) + bo,  WVO_h = Wv_h . Wo_h
//   out_row   = LN2(h + FFN(h)),  h = LN1(xp + attn_out)
// 2 kernels: K1 = {qk-role (self-sufficient: binary-search rows + in-LDS Wk
// transpose), WVO tiled GEMM, W1/W2 fp16 packing, bvoP, offs-scan} as disjoint
// block ranges (overlap in HW, no inter-role deps); K2 = fused attn+tail.

#define BMOL 512

// ---------------- K1: all independent work in one launch ----------------
// block ranges: [0,512) qk | [512,640) WVO | [640,672) W1p | [672,704) W2p
//               | [704,712) bvoP | [712,712+noff) offs
__global__ __launch_bounds__(256) void k_front(
    const float* __restrict__ AF, const float* __restrict__ Wq,
    const float* __restrict__ bq, const float* __restrict__ Wk,
    const float* __restrict__ Wv, const float* __restrict__ Wo,
    const float* __restrict__ bv, const float* __restrict__ W1,
    const float* __restrict__ W2,
    const int* __restrict__ mol, const int* __restrict__ picked,
    int N, int noff,
    int* __restrict__ offs, float* __restrict__ QK,
    __half* __restrict__ WVOp, float* __restrict__ bvoP,
    __half* __restrict__ W1p, __half* __restrict__ W2p)
{
    __shared__ float lds[18560];            // 74240B, role-dependent layout
    __shared__ int rows[8];
    int bid = blockIdx.x, t = threadIdx.x;

    if (bid < 512) {
        // ---- qk-role: 8 molecules x 1 head per block ----
        int h = bid >> 6, m0 = (bid & 63) * 8;
        float* wkT = lds;                   // [128][129]
        float* xp  = lds + 16512;           // [8][128]
        float* qs  = lds + 17536;           // [8][128]
        if (t < 8) {                        // picked row via lower_bound(mol, m)
            int m = m0 + t;
            int lo = 0, hi = N;
            while (lo < hi) { int mid = (lo + hi) >> 1; if (mol[mid] < m) lo = mid + 1; else hi = mid; }
            rows[t] = lo + picked[m];
        }
        {                                   // Wk_h -> LDS transposed [kd][d]
            int r = t >> 5, kd0 = (t & 31) * 4;
            #pragma unroll
            for (int rep = 0; rep < 16; ++rep) {
                int row = r + rep * 8;
                float4 v = *(const float4*)(Wk + (size_t)row * 1024 + h * 128 + kd0);
                wkT[(kd0 + 0) * 129 + row] = v.x;
                wkT[(kd0 + 1) * 129 + row] = v.y;
                wkT[(kd0 + 2) * 129 + row] = v.z;
                wkT[(kd0 + 3) * 129 + row] = v.w;
            }
        }
        __syncthreads();
        {                                   // stage 8 picked rows
            int m = t >> 5, d4 = t & 31;
            *(float4*)(xp + m * 128 + d4 * 4) =
                ((const float4*)(AF + (size_t)rows[m] * 128))[d4];
        }
        __syncthreads();
        int c = t & 127, mg = t >> 7;       // mg in {0,1}, 4 mols each
        {                                   // q = xp.Wq_h + bq_h
            const float* wq = Wq + h * 128 + c;
            const float* x0 = xp + (mg * 4 + 0) * 128;
            const float* x1 = xp + (mg * 4 + 1) * 128;
            const float* x2 = xp + (mg * 4 + 2) * 128;
            const float* x3 = xp + (mg * 4 + 3) * 128;
            float a0 = 0.f, a1 = 0.f, a2 = 0.f, a3 = 0.f;
            #pragma unroll 8
            for (int k = 0; k < 128; ++k) {
                float w = wq[(size_t)k * 1024];
                a0 += x0[k] * w; a1 += x1[k] * w; a2 += x2[k] * w; a3 += x3[k] * w;
            }
            float bb = bq[h * 128 + c];
            qs[(mg * 4 + 0) * 128 + c] = a0 + bb;
            qs[(mg * 4 + 1) * 128 + c] = a1 + bb;
            qs[(mg * 4 + 2) * 128 + c] = a2 + bb;
            qs[(mg * 4 + 3) * 128 + c] = a3 + bb;
        }
        __syncthreads();
        {                                   // QK = q.WkT_h
            const float* q0 = qs + (mg * 4 + 0) * 128;
            const float* q1 = qs + (mg * 4 + 1) * 128;
            const float* q2 = qs + (mg * 4 + 2) * 128;
            const float* q3 = qs + (mg * 4 + 3) * 128;
            float a0 = 0.f, a1 = 0.f, a2 = 0.f, a3 = 0.f;
            #pragma unroll 8
            for (int k = 0; k < 128; ++k) {
                float w = wkT[k * 129 + c];
                a0 += q0[k] * w; a1 += q1[k] * w; a2 += q2[k] * w; a3 += q3[k] * w;
            }
            QK[(size_t)(m0 + mg * 4 + 0) * 1024 + h * 128 + c] = a0;
            QK[(size_t)(m0 + mg * 4 + 1) * 1024 + h * 128 + c] = a1;
            QK[(size_t)(m0 + mg * 4 + 2) * 1024 + h * 128 + c] = a2;
            QK[(size_t)(m0 + mg * 4 + 3) * 1024 + h * 128 + c] = a3;
        }
        return;
    }
    bid -= 512;
    if (bid < 128) {
        // ---- WVO tiled GEMM: per head C[d][c] = sum_kd Wv[d,h,kd]*Wo[h,kd,c] ----
        int h = bid >> 4, tile = bid & 15;
        int dt = tile >> 2, ct = tile & 3;
        float* Avs = lds;                   // [32][33]
        float* Bos = lds + 32 * 33;         // [32][33]
        int ry = t >> 5, cx = t & 31;
        float acc[4] = {0.f, 0.f, 0.f, 0.f};
        for (int kk = 0; kk < 4; ++kk) {
            int r = t >> 3, e0 = (t & 7) * 4;
            float4 va = *(const float4*)(Wv + (size_t)(dt * 32 + r) * 1024 + h * 128 + kk * 32 + e0);
            Avs[r * 33 + e0] = va.x; Avs[r * 33 + e0 + 1] = va.y;
            Avs[r * 33 + e0 + 2] = va.z; Avs[r * 33 + e0 + 3] = va.w;
            float4 vb = *(const float4*)(Wo + (size_t)h * 16384 + (size_t)(kk * 32 + r) * 128 + ct * 32 + e0);
            Bos[r * 33 + e0] = vb.x; Bos[r * 33 + e0 + 1] = vb.y;
            Bos[r * 33 + e0 + 2] = vb.z; Bos[r * 33 + e0 + 3] = vb.w;
            __syncthreads();
            #pragma unroll
            for (int k = 0; k < 32; ++k) {
                float b = Bos[k * 33 + cx];
                #pragma unroll
                for (int i = 0; i < 4; ++i) acc[i] += Avs[(ry * 4 + i) * 33 + k] * b;
            }
            __syncthreads();
        }
        // packed write: k = h*128 + dt*32 + ry*4 + i; c = ct*32 + cx
        __half2 p0 = __floats2half2_rn(acc[0], acc[1]);
        __half2 p1 = __floats2half2_rn(acc[2], acc[3]);
        __half* dst = WVOp + (size_t)(h * 16 + dt * 4 + (ry >> 1)) * 1024
                           + (ct * 32 + cx) * 8 + (ry & 1) * 4;
        *(float2*)dst = *(float2*)&p0;      // p0,p1 contiguous? write separately:
        ((__half2*)dst)[0] = p0; ((__half2*)dst)[1] = p1;
        return;
    }
    bid -= 128;
    if (bid < 32) {                         // W1p[(k>>3)][f][k&7], K=128, F=512
        int g = bid * 256 + t;
        int kg = g >> 9, f = g & 511;
        __half2 p[4];
        #pragma unroll
        for (int j = 0; j < 4; ++j) {
            float a = W1[(size_t)(kg * 8 + 2 * j) * 512 + f];
            float b = W1[(size_t)(kg * 8 + 2 * j + 1) * 512 + f];
            p[j] = __floats2half2_rn(a, b);
        }
        *(float4*)(W1p + (size_t)kg * 4096 + f * 8) = *(float4*)p;
        return;
    }
    bid -= 32;
    if (bid < 32) {                         // W2p[(f>>3)][c][f&7], K=512, C=128
        int g = bid * 256 + t;
        int fg = g >> 7, c = g & 127;
        __half2 p[4];
        #pragma unroll
        for (int j = 0; j < 4; ++j) {
            float a = W2[(size_t)(fg * 8 + 2 * j) * 128 + c];
            float b = W2[(size_t)(fg * 8 + 2 * j + 1) * 128 + c];
            p[j] = __floats2half2_rn(a, b);
        }
        *(float4*)(W2p + (size_t)fg * 1024 + c * 8) = *(float4*)p;
        return;
    }
    bid -= 32;
    if (bid < 8) {                          // bvoP[j][c] = sum_{hk in j-th 128} bv[hk]*Wo[hk,c]
        int half = t >> 7, c = t & 127;
        float acc = 0.f;
        #pragma unroll 4
        for (int kk = 0; kk < 64; ++kk) {
            int k = bid * 128 + half * 64 + kk;
            acc += bv[k] * Wo[(size_t)k * 128 + c];
        }
        lds[half * 128 + c] = acc;
        __syncthreads();
        if (t < 128) bvoP[bid * 128 + t] = lds[t] + lds[128 + t];
        return;
    }
    bid -= 8;
    {                                       // offs scan
        int i = bid * 256 + t;
        if (i < N) {
            if (i == 0) { offs[0] = 0; offs[BMOL] = N; }
            else if (mol[i] != mol[i - 1]) offs[mol[i]] = i;
        }
    }
}

// ---------------- K2: fused attention + tail, one block per molecule ----------------
__global__ __launch_bounds__(256) void k_attn_tail(
    const float* __restrict__ AF, const float* __restrict__ QK,
    const int* __restrict__ offs, const int* __restrict__ picked,
    const __half* __restrict__ WVOp, const float* __restrict__ bvoP,
    const float* __restrict__ bo,
    const float* __restrict__ g1, const float* __restrict__ be1,
    const __half* __restrict__ W1p, const float* __restrict__ b1,
    const __half* __restrict__ W2p, const float* __restrict__ b2,
    const float* __restrict__ g2, const float* __restrict__ be2,
    float* __restrict__ out)
{
    int b = blockIdx.x, t = threadIdx.x;
    int o0 = offs[b], cnt = offs[b + 1] - o0;
    __shared__ __half xs[128][136];         // fp16 X; row = 272B
    __shared__ float qs[8][132];
    __shared__ float s[8 * 136];
    __shared__ float mh[8], lh[8];
    __shared__ float ws[1024];              // WX (attention-weighted X)
    __shared__ float h1raw[128], h1n[128], ms[512];

    const float4* af4 = (const float4*)(AF + (size_t)o0 * 128);
    for (int p = t; p < cnt * 32; p += 256) {   // stage X once, f32->f16
        int i = p >> 5, d4 = p & 31;
        float4 v = af4[p];
        float2 st;
        ((__half2*)&st)[0] = __floats2half2_rn(v.x, v.y);
        ((__half2*)&st)[1] = __floats2half2_rn(v.z, v.w);
        *(float2*)(&xs[i][d4 * 4]) = st;
    }
    {                                       // stage QK row (4KB)
        int i = t >> 5, d4 = t & 31;
        *(float4*)(&qs[i][d4 * 4]) = ((const float4*)(QK + (size_t)b * 1024))[t];
    }
    __syncthreads();
    const float scale = 0.08838834764831843f;   // 1/sqrt(128)
    for (int p = t; p < cnt * 8; p += 256) {    // scores
        int i = p >> 3, h = p & 7;
        float acc = 0.f;
        #pragma unroll 8
        for (int dq = 0; dq < 16; ++dq) {
            float4 xraw = ((const float4*)xs[i])[dq];
            const __half2* xh = (const __half2*)&xraw;
            float4 q0 = ((const float4*)qs[h])[dq * 2];
            float4 q1 = ((const float4*)qs[h])[dq * 2 + 1];
            float2 x0 = __half22float2(xh[0]), x1 = __half22float2(xh[1]);
            float2 x2 = __half22float2(xh[2]), x3 = __half22float2(xh[3]);
            acc += x0.x * q0.x + x0.y * q0.y + x1.x * q0.z + x1.y * q0.w
                 + x2.x * q1.x + x2.y * q1.y + x3.x * q1.z + x3.y * q1.w;
        }
        s[h * 136 + i] = acc * scale;
    }
    __syncthreads();
    {                                       // softmax stats: 32 lanes per head
        int h = t >> 5, lane = t & 31;
        float m = -1e30f;
        for (int i = lane; i < cnt; i += 32) m = fmaxf(m, s[h * 136 + i]);
        #pragma unroll
        for (int off = 16; off; off >>= 1) m = fmaxf(m, __shfl_xor(m, off));
        float l = 0.f;
        for (int i = lane; i < cnt; i += 32) l += __expf(s[h * 136 + i] - m);
        #pragma unroll
        for (int off = 16; off; off >>= 1) l += __shfl_xor(l, off);
        if (lane == 0) { mh[h] = m; lh[h] = 1.f / l; }
    }
    __syncthreads();
    for (int p = t; p < cnt * 8; p += 256) {
        int i = p >> 3, h = p & 7;
        s[h * 136 + i] = __expf(s[h * 136 + i] - mh[h]) * lh[h];
    }
    __syncthreads();
    {                                       // WX[h][:] = sum_i attn(i,h) x_i -> LDS
        int hw = t >> 5, qq = t & 31;
        float4 a4 = {0.f, 0.f, 0.f, 0.f};
        for (int i = 0; i < cnt; ++i) {
            float sv = s[hw * 136 + i];
            float2 xraw = *(const float2*)(&xs[i][qq * 4]);
            const __half2* xh = (const __half2*)&xraw;
            float2 x0 = __half22float2(xh[0]), x1 = __half22float2(xh[1]);
            a4.x += sv * x0.x; a4.y += sv * x0.y; a4.z += sv * x1.x; a4.w += sv * x1.y;
        }
        *(float4*)(&ws[hw * 128 + qq * 4]) = a4;
    }
    __syncthreads();
    // ---- tail phase A: attn_out[c] = ws . WVO[:,c], K=1024 split over lane pairs ----
    int c = t >> 1, kh = t & 1;
    {
        const __half* wp = WVOp + (size_t)(kh * 64) * 1024 + c * 8;
        float acc = 0.f;
        #pragma unroll 8
        for (int g = 0; g < 64; ++g) {
            float4 raw = *(const float4*)(wp + (size_t)g * 1024);
            const __half2* hp = (const __half2*)&raw;
            const float* wk = ws + kh * 512 + g * 8;
            float2 w0 = __half22float2(hp[0]), w1 = __half22float2(hp[1]);
            float2 w2 = __half22float2(hp[2]), w3 = __half22float2(hp[3]);
            acc += wk[0] * w0.x + wk[1] * w0.y + wk[2] * w1.x + wk[3] * w1.y
                 + wk[4] * w2.x + wk[5] * w2.y + wk[6] * w3.x + wk[7] * w3.y;
        }
        acc += __shfl_xor(acc, 1);
        if (!kh) {
            float bias = bo[c];
            #pragma unroll
            for (int j = 0; j < 8; ++j) bias += bvoP[j * 128 + c];
            int row = o0 + picked[b];
            h1raw[c] = acc + bias + AF[(size_t)row * 128 + c];
        }
    }
    __syncthreads();
    {   // LN1 (redundant per wave)
        int l = t & 63;
        float a = h1raw[l], bb = h1raw[l + 64];
        float sm = a + bb, sq = a * a + bb * bb;
        #pragma unroll
        for (int off = 32; off; off >>= 1) { sm += __shfl_xor(sm, off); sq += __shfl_xor(sq, off); }
        float m = sm * (1.f / 128.f), var = sq * (1.f / 128.f) - m * m;
        float rs = rsqrtf(var + 1e-3f);
        if (t < 128) h1n[t] = (h1raw[t] - m) * rs * g1[t] + be1[t];
    }
    __syncthreads();
    {   // phase B: mid[f] = relu(h1n.W1[:,f] + b1), f = t and t+256
        float acc0 = 0.f, acc1 = 0.f;
        const __half* wp0 = W1p + t * 8;
        const __half* wp1 = W1p + (t + 256) * 8;
        #pragma unroll 8
        for (int g = 0; g < 16; ++g) {
            float4 r0 = *(const float4*)(wp0 + (size_t)g * 4096);
            float4 r1 = *(const float4*)(wp1 + (size_t)g * 4096);
            const float* hk = h1n + g * 8;
            const __half2* a0 = (const __half2*)&r0;
            const __half2* a1 = (const __half2*)&r1;
            #pragma unroll
            for (int j = 0; j < 4; ++j) {
                float2 u = __half22float2(a0[j]), v = __half22float2(a1[j]);
                acc0 += hk[2 * j] * u.x + hk[2 * j + 1] * u.y;
                acc1 += hk[2 * j] * v.x + hk[2 * j + 1] * v.y;
            }
        }
        ms[t] = fmaxf(acc0 + b1[t], 0.f);
        ms[t + 256] = fmaxf(acc1 + b1[t + 256], 0.f);
    }
    __syncthreads();
    {   // phase C: outraw[c] = ms . W2[:,c] + b2 + h1n, K=512 split over lane pairs
        const __half* wp = W2p + (size_t)(kh * 32) * 1024 + c * 8;
        float acc = 0.f;
        #pragma unroll 8
        for (int g = 0; g < 32; ++g) {
            float4 raw = *(const float4*)(wp + (size_t)g * 1024);
            const __half2* hp = (const __half2*)&raw;
            const float* mk = ms + kh * 256 + g * 8;
            float2 w0 = __half22float2(hp[0]), w1 = __half22float2(hp[1]);
            float2 w2 = __half22float2(hp[2]), w3 = __half22float2(hp[3]);
            acc += mk[0] * w0.x + mk[1] * w0.y + mk[2] * w1.x + mk[3] * w1.y
                 + mk[4] * w2.x + mk[5] * w2.y + mk[6] * w3.x + mk[7] * w3.y;
        }
        acc += __shfl_xor(acc, 1);
        if (!kh) h1raw[c] = acc + b2[c] + h1n[c];
    }
    __syncthreads();
    {   // LN2 (redundant per wave) -> global out
        int l = t & 63;
        float a = h1raw[l], bb = h1raw[l + 64];
        float sm = a + bb, sq = a * a + bb * bb;
        #pragma unroll
        for (int off = 32; off; off >>= 1) { sm += __shfl_xor(sm, off); sq += __shfl_xor(sq, off); }
        float m = sm * (1.f / 128.f), var = sq * (1.f / 128.f) - m * m;
        float rs = rsqrtf(var + 1e-3f);
        if (t < 128) out[(size_t)b * 128 + t] = (h1raw[t] - m) * rs * g2[t] + be2[t];
    }
}

extern "C" void kernel_launch(void* const* d_in, const int* in_sizes, int n_in,
                              void* d_out, int out_size, void* d_ws, size_t ws_size,
                              hipStream_t stream) {
    const float* AF  = (const float*)d_in[0];
    const float* Wq  = (const float*)d_in[1];
    const float* bq  = (const float*)d_in[2];
    const float* Wk  = (const float*)d_in[3];
    const float* Wv  = (const float*)d_in[5];
    const float* bv  = (const float*)d_in[6];
    const float* Wo  = (const float*)d_in[7];
    const float* bo  = (const float*)d_in[8];
    const float* W1  = (const float*)d_in[9];
    const float* b1  = (const float*)d_in[10];
    const float* W2  = (const float*)d_in[11];
    const float* b2  = (const float*)d_in[12];
    const float* g1  = (const float*)d_in[13];
    const float* be1 = (const float*)d_in[14];
    const float* g2  = (const float*)d_in[15];
    const float* be2 = (const float*)d_in[16];
    const int* mol    = (const int*)d_in[17];
    const int* picked = (const int*)d_in[18];
    int N = in_sizes[0] / 128;
    int noff = (N + 255) / 256;

    char* ws = (char*)d_ws;
    int*    offs = (int*)ws;                      // 513 ints (4KB slot)
    __half* WVOp = (__half*)(ws + 4096);          // packed [128][128][8] 256KB
    float*  bvoP = (float*)(ws + 266240);         // [8][128] 4KB
    __half* W1p  = (__half*)(ws + 270336);        // packed [16][512][8] 128KB
    __half* W2p  = (__half*)(ws + 401408);        // packed [64][128][8] 128KB
    float*  QK   = (float*)(ws + 532480);         // [512][1024] 2MB

    k_front<<<712 + noff, 256, 0, stream>>>(AF, Wq, bq, Wk, Wv, Wo, bv, W1, W2,
                                            mol, picked, N, noff,
                                            offs, QK, WVOp, bvoP, W1p, W2p);
    k_attn_tail<<<BMOL, 256, 0, stream>>>(AF, QK, offs, picked, WVOp, bvoP, bo,
                                          g1, be1, W1p, b1, W2p, b2, g2, be2,
                                          (float*)d_out);
}

// Round 6
// 57.015 us; speedup vs baseline: 2.5278x; 1.0473x over previous
//
#include <hip/hip_runtime.h>
#include <hip/hip_bf16.h>
#include <hip/hip_fp16.h>

// TransformerEncoderReadout: only the picked atom's output row is needed.
//   QK[b,h,:] = xp_b . WQK_h + bqk_h,   WQK_h = Wq_h . Wk_h^T  (q.bk drops out)
//   s(i,h)    = x_i . QK[b,h,:] / sqrt(128); softmax over i within molecule
//   WX[h,:]   = sum_i attn(i,h) x_i      (softmax sums to 1 -> bv folds out)
//   attn_out  = WX . WVO + (bv.Wo) + bo, WVO_h = Wv_h . Wo_h
//   out_row   = LN2(h + FFN(h)),  h = LN1(xp + attn_out)
// K1: small fused-weight GEMMs + packing + offsets (all independent roles).
// K2: one block per molecule, 512 threads: computes its own QK row from WQKp,
//     then scores/softmax/WX/tail entirely in LDS. No QK global round-trip.

#define BMOL 512

// ---------------- K1 block ranges ----------------
// [0,128) WVOp | [128,256) WQKp | [256,288) W1p | [288,320) W2p
// [320,328) bvoP | [328,336) bqk | [336,336+noff) offs
__global__ __launch_bounds__(256) void k_front(
    const float* __restrict__ Wq, const float* __restrict__ bq,
    const float* __restrict__ Wk, const float* __restrict__ Wv,
    const float* __restrict__ Wo, const float* __restrict__ bv,
    const float* __restrict__ W1, const float* __restrict__ W2,
    const int* __restrict__ mol, int N, int noff,
    int* __restrict__ offs, __half* __restrict__ WVOp,
    __half* __restrict__ WQKp, float* __restrict__ bqk,
    float* __restrict__ bvoP, __half* __restrict__ W1p, __half* __restrict__ W2p)
{
    __shared__ float lds[2176];             // 2x [32][33] tiles
    int bid = blockIdx.x, t = threadIdx.x;

    if (bid < 256) {
        // ---- tiled GEMM: 32x32 output tile, K=128 ----
        // bid<128: WVO[(h*128+d)][c] = sum_kd Wv[d,h,kd]*Wo[h,kd,c]
        // else   : WQK[(h*128+k)][d] = sum_kd Wq[k,h,kd]*Wk[d,h,kd]
        bool qk = bid >= 128;
        int rel = bid & 127;
        int h = rel >> 4, tile = rel & 15;
        int dt = tile >> 2, ct = tile & 3;
        float* Avs = lds;                   // [32][33]
        float* Bos = lds + 1056;            // [32][33]
        int ry = t >> 5, cx = t & 31;
        float acc[4] = {0.f, 0.f, 0.f, 0.f};
        const float* Asrc = qk ? Wq : Wv;
        for (int kk = 0; kk < 4; ++kk) {
            int r = t >> 3, e0 = (t & 7) * 4;
            float4 va = *(const float4*)(Asrc + (size_t)(dt * 32 + r) * 1024 + h * 128 + kk * 32 + e0);
            Avs[r * 33 + e0] = va.x; Avs[r * 33 + e0 + 1] = va.y;
            Avs[r * 33 + e0 + 2] = va.z; Avs[r * 33 + e0 + 3] = va.w;
            if (qk) {                       // B[kd][d] = Wk[d,h,kd] (transposed load)
                float4 vb = *(const float4*)(Wk + (size_t)(ct * 32 + r) * 1024 + h * 128 + kk * 32 + e0);
                Bos[(e0 + 0) * 33 + r] = vb.x;
                Bos[(e0 + 1) * 33 + r] = vb.y;
                Bos[(e0 + 2) * 33 + r] = vb.z;
                Bos[(e0 + 3) * 33 + r] = vb.w;
            } else {                        // B[kd][c] = Wo[h,kd,c]
                float4 vb = *(const float4*)(Wo + (size_t)h * 16384 + (size_t)(kk * 32 + r) * 128 + ct * 32 + e0);
                Bos[r * 33 + e0] = vb.x; Bos[r * 33 + e0 + 1] = vb.y;
                Bos[r * 33 + e0 + 2] = vb.z; Bos[r * 33 + e0 + 3] = vb.w;
            }
            __syncthreads();
            #pragma unroll
            for (int k = 0; k < 32; ++k) {
                float b = Bos[k * 33 + cx];
                #pragma unroll
                for (int i = 0; i < 4; ++i) acc[i] += Avs[(ry * 4 + i) * 33 + k] * b;
            }
            __syncthreads();
        }
        // packed [k>>3][c][k&7]: k = h*128 + dt*32 + ry*4 + i; c = ct*32+cx
        __half2 p0 = __floats2half2_rn(acc[0], acc[1]);
        __half2 p1 = __floats2half2_rn(acc[2], acc[3]);
        __half* dst = (qk ? WQKp : WVOp)
                    + (size_t)(h * 16 + dt * 4 + (ry >> 1)) * 1024
                    + (ct * 32 + cx) * 8 + (ry & 1) * 4;
        ((__half2*)dst)[0] = p0; ((__half2*)dst)[1] = p1;
        return;
    }
    bid -= 256;
    if (bid < 32) {                         // W1p[(k>>3)][f][k&7], K=128, F=512
        int g = bid * 256 + t;
        int kg = g >> 9, f = g & 511;
        __half2 p[4];
        #pragma unroll
        for (int j = 0; j < 4; ++j) {
            float a = W1[(size_t)(kg * 8 + 2 * j) * 512 + f];
            float b = W1[(size_t)(kg * 8 + 2 * j + 1) * 512 + f];
            p[j] = __floats2half2_rn(a, b);
        }
        *(float4*)(W1p + (size_t)kg * 4096 + f * 8) = *(float4*)p;
        return;
    }
    bid -= 32;
    if (bid < 32) {                         // W2p[(f>>3)][c][f&7], K=512, C=128
        int g = bid * 256 + t;
        int fg = g >> 7, c = g & 127;
        __half2 p[4];
        #pragma unroll
        for (int j = 0; j < 4; ++j) {
            float a = W2[(size_t)(fg * 8 + 2 * j) * 128 + c];
            float b = W2[(size_t)(fg * 8 + 2 * j + 1) * 128 + c];
            p[j] = __floats2half2_rn(a, b);
        }
        *(float4*)(W2p + (size_t)fg * 1024 + c * 8) = *(float4*)p;
        return;
    }
    bid -= 32;
    if (bid < 8) {                          // bvoP[j][c] = sum_{hk in j-th 128} bv[hk]*Wo[hk,c]
        int half = t >> 7, c = t & 127;
        float acc = 0.f;
        #pragma unroll 4
        for (int kk = 0; kk < 64; ++kk) {
            int k = bid * 128 + half * 64 + kk;
            acc += bv[k] * Wo[(size_t)k * 128 + c];
        }
        lds[half * 128 + c] = acc;
        __syncthreads();
        if (t < 128) bvoP[bid * 128 + t] = lds[t] + lds[128 + t];
        return;
    }
    bid -= 8;
    if (bid < 8) {                          // bqk[h][d] = sum_kd bq[h,kd]*Wk[d,h,kd]
        int h = bid;
        if (t < 128) {
            const float* wk = Wk + (size_t)t * 1024 + h * 128;
            const float* bqh = bq + h * 128;
            float acc = 0.f;
            #pragma unroll 4
            for (int kd = 0; kd < 128; ++kd) acc += bqh[kd] * wk[kd];
            bqk[h * 128 + t] = acc;
        }
        return;
    }
    bid -= 8;
    {                                       // offs scan
        int i = bid * 256 + t;
        if (i < N) {
            if (i == 0) { offs[0] = 0; offs[BMOL] = N; }
            else if (mol[i] != mol[i - 1]) offs[mol[i]] = i;
        }
    }
}

// ---------------- K2: fused QK + attention + tail, one block per molecule ----------------
__global__ __launch_bounds__(512) void k_attn_tail(
    const float* __restrict__ AF, const int* __restrict__ offs,
    const int* __restrict__ picked,
    const __half* __restrict__ WQKp, const float* __restrict__ bqk,
    const __half* __restrict__ WVOp, const float* __restrict__ bvoP,
    const float* __restrict__ bo,
    const float* __restrict__ g1, const float* __restrict__ be1,
    const __half* __restrict__ W1p, const float* __restrict__ b1,
    const __half* __restrict__ W2p, const float* __restrict__ b2,
    const float* __restrict__ g2, const float* __restrict__ be2,
    float* __restrict__ out)
{
    int b = blockIdx.x, t = threadIdx.x;
    int o0 = offs[b], cnt = offs[b + 1] - o0;
    __shared__ __half xs[128][136];         // fp16 X; row = 272B
    __shared__ float qs[8][132];            // scaled QK row
    __shared__ float s[8 * 136];
    __shared__ float mh[8], lh[8];
    __shared__ float ws[2][1024];           // WX partials (i-split 2-way)
    __shared__ float xp[128];               // picked row fp32
    __shared__ float h1raw[128], h1n[128], ms[512];
    const float scale = 0.08838834764831843f;   // 1/sqrt(128)

    const float4* af4 = (const float4*)(AF + (size_t)o0 * 128);
    for (int p = t; p < cnt * 32; p += 512) {   // stage X once, f32->f16
        int i = p >> 5, d4 = p & 31;
        float4 v = af4[p];
        float2 st;
        ((__half2*)&st)[0] = __floats2half2_rn(v.x, v.y);
        ((__half2*)&st)[1] = __floats2half2_rn(v.z, v.w);
        *(float2*)(&xs[i][d4 * 4]) = st;
    }
    if (t < 128) {                          // stage picked row fp32
        int row = o0 + picked[b];
        xp[t] = AF[(size_t)row * 128 + t];
    }
    __syncthreads();
    {   // ---- QK row: qs[h][d] = (xp . WQK_h[:,d] + bqk)*scale; 2 outputs/thread ----
        int h = t >> 6, d0 = (t & 63) * 2;
        const __half* wp = WQKp + ((size_t)(h * 16) * 128 + d0) * 8;
        float acc0 = 0.f, acc1 = 0.f;
        #pragma unroll 4
        for (int kg = 0; kg < 16; ++kg) {
            float4 r0 = *(const float4*)(wp + (size_t)kg * 1024);
            float4 r1 = *(const float4*)(wp + (size_t)kg * 1024 + 8);
            const float* xk = xp + kg * 8;
            const __half2* h0 = (const __half2*)&r0;
            const __half2* h1 = (const __half2*)&r1;
            #pragma unroll
            for (int j = 0; j < 4; ++j) {
                float2 u = __half22float2(h0[j]), v = __half22float2(h1[j]);
                acc0 += xk[2 * j] * u.x + xk[2 * j + 1] * u.y;
                acc1 += xk[2 * j] * v.x + xk[2 * j + 1] * v.y;
            }
        }
        qs[h][d0]     = (acc0 + bqk[h * 128 + d0]) * scale;
        qs[h][d0 + 1] = (acc1 + bqk[h * 128 + d0 + 1]) * scale;
    }
    __syncthreads();
    for (int p = t; p < cnt * 8; p += 512) {    // scores (scale pre-folded)
        int i = p >> 3, h = p & 7;
        float acc = 0.f;
        #pragma unroll 8
        for (int dq = 0; dq < 16; ++dq) {
            float4 xraw = ((const float4*)xs[i])[dq];
            const __half2* xh = (const __half2*)&xraw;
            float4 q0 = ((const float4*)qs[h])[dq * 2];
            float4 q1 = ((const float4*)qs[h])[dq * 2 + 1];
            float2 x0 = __half22float2(xh[0]), x1 = __half22float2(xh[1]);
            float2 x2 = __half22float2(xh[2]), x3 = __half22float2(xh[3]);
            acc += x0.x * q0.x + x0.y * q0.y + x1.x * q0.z + x1.y * q0.w
                 + x2.x * q1.x + x2.y * q1.y + x3.x * q1.z + x3.y * q1.w;
        }
        s[h * 136 + i] = acc;
    }
    __syncthreads();
    {   // softmax stats: one 64-lane wave per head
        int h = t >> 6, lane = t & 63;
        float m = -1e30f;
        for (int i = lane; i < cnt; i += 64) m = fmaxf(m, s[h * 136 + i]);
        #pragma unroll
        for (int off = 32; off; off >>= 1) m = fmaxf(m, __shfl_xor(m, off));
        float l = 0.f;
        for (int i = lane; i < cnt; i += 64) l += __expf(s[h * 136 + i] - m);
        #pragma unroll
        for (int off = 32; off; off >>= 1) l += __shfl_xor(l, off);
        if (lane == 0) { mh[h] = m; lh[h] = 1.f / l; }
    }
    __syncthreads();
    for (int p = t; p < cnt * 8; p += 512) {
        int i = p >> 3, h = p & 7;
        s[h * 136 + i] = __expf(s[h * 136 + i] - mh[h]) * lh[h];
    }
    __syncthreads();
    {   // WX partials: thread = (ih, hw, qq); i interleaved 2-way
        int ih = t >> 8, hw = (t >> 5) & 7, qq = t & 31;
        float4 a4 = {0.f, 0.f, 0.f, 0.f};
        for (int i = ih; i < cnt; i += 2) {
            float sv = s[hw * 136 + i];
            float2 xraw = *(const float2*)(&xs[i][qq * 4]);
            const __half2* xh = (const __half2*)&xraw;
            float2 x0 = __half22float2(xh[0]), x1 = __half22float2(xh[1]);
            a4.x += sv * x0.x; a4.y += sv * x0.y; a4.z += sv * x1.x; a4.w += sv * x1.y;
        }
        *(float4*)(&ws[ih][hw * 128 + qq * 4]) = a4;
    }
    __syncthreads();
    int c = t >> 2, kq = t & 3;
    {   // tail A: attn_out[c] = ws . WVO[:,c], K=1024 split 4-way over quads
        const __half* wp = WVOp + ((size_t)(kq * 32) * 128 + c) * 8;
        float acc = 0.f;
        #pragma unroll 8
        for (int g = 0; g < 32; ++g) {
            float4 raw = *(const float4*)(wp + (size_t)g * 1024);
            const __half2* hp = (const __half2*)&raw;
            int kb = (kq * 32 + g) * 8;
            const float* w0a = ws[0] + kb;
            const float* w1a = ws[1] + kb;
            float2 u0 = __half22float2(hp[0]), u1 = __half22float2(hp[1]);
            float2 u2 = __half22float2(hp[2]), u3 = __half22float2(hp[3]);
            acc += (w0a[0] + w1a[0]) * u0.x + (w0a[1] + w1a[1]) * u0.y
                 + (w0a[2] + w1a[2]) * u1.x + (w0a[3] + w1a[3]) * u1.y
                 + (w0a[4] + w1a[4]) * u2.x + (w0a[5] + w1a[5]) * u2.y
                 + (w0a[6] + w1a[6]) * u3.x + (w0a[7] + w1a[7]) * u3.y;
        }
        acc += __shfl_xor(acc, 1);
        acc += __shfl_xor(acc, 2);
        if (kq == 0) {
            float bias = bo[c];
            #pragma unroll
            for (int j = 0; j < 8; ++j) bias += bvoP[j * 128 + c];
            h1raw[c] = acc + bias + xp[c];
        }
    }
    __syncthreads();
    {   // LN1 (redundant per wave)
        int l = t & 63;
        float a = h1raw[l], bb = h1raw[l + 64];
        float sm = a + bb, sq = a * a + bb * bb;
        #pragma unroll
        for (int off = 32; off; off >>= 1) { sm += __shfl_xor(sm, off); sq += __shfl_xor(sq, off); }
        float m = sm * (1.f / 128.f), var = sq * (1.f / 128.f) - m * m;
        float rs = rsqrtf(var + 1e-3f);
        if (t < 128) h1n[t] = (h1raw[t] - m) * rs * g1[t] + be1[t];
    }
    __syncthreads();
    {   // phase B: ms[f] = relu(h1n . W1[:,f] + b1), one output per thread
        const __half* wp = W1p + t * 8;
        float acc = 0.f;
        #pragma unroll 8
        for (int kg = 0; kg < 16; ++kg) {
            float4 raw = *(const float4*)(wp + (size_t)kg * 4096);
            const __half2* hp = (const __half2*)&raw;
            const float* hk = h1n + kg * 8;
            #pragma unroll
            for (int j = 0; j < 4; ++j) {
                float2 u = __half22float2(hp[j]);
                acc += hk[2 * j] * u.x + hk[2 * j + 1] * u.y;
            }
        }
        ms[t] = fmaxf(acc + b1[t], 0.f);
    }
    __syncthreads();
    {   // phase C: out[c] = ms . W2[:,c] + b2 + h1n, K=512 split 4-way
        const __half* wp = W2p + ((size_t)(kq * 16) * 128 + c) * 8;
        float acc = 0.f;
        #pragma unroll 8
        for (int g = 0; g < 16; ++g) {
            float4 raw = *(const float4*)(wp + (size_t)g * 1024);
            const __half2* hp = (const __half2*)&raw;
            const float* mk = ms + (kq * 16 + g) * 8;
            float2 u0 = __half22float2(hp[0]), u1 = __half22float2(hp[1]);
            float2 u2 = __half22float2(hp[2]), u3 = __half22float2(hp[3]);
            acc += mk[0] * u0.x + mk[1] * u0.y + mk[2] * u1.x + mk[3] * u1.y
                 + mk[4] * u2.x + mk[5] * u2.y + mk[6] * u3.x + mk[7] * u3.y;
        }
        acc += __shfl_xor(acc, 1);
        acc += __shfl_xor(acc, 2);
        if (kq == 0) h1raw[c] = acc + b2[c] + h1n[c];
    }
    __syncthreads();
    {   // LN2 (redundant per wave) -> global out
        int l = t & 63;
        float a = h1raw[l], bb = h1raw[l + 64];
        float sm = a + bb, sq = a * a + bb * bb;
        #pragma unroll
        for (int off = 32; off; off >>= 1) { sm += __shfl_xor(sm, off); sq += __shfl_xor(sq, off); }
        float m = sm * (1.f / 128.f), var = sq * (1.f / 128.f) - m * m;
        float rs = rsqrtf(var + 1e-3f);
        if (t < 128) out[(size_t)b * 128 + t] = (h1raw[t] - m) * rs * g2[t] + be2[t];
    }
}

extern "C" void kernel_launch(void* const* d_in, const int* in_sizes, int n_in,
                              void* d_out, int out_size, void* d_ws, size_t ws_size,
                              hipStream_t stream) {
    const float* AF  = (const float*)d_in[0];
    const float* Wq  = (const float*)d_in[1];
    const float* bq  = (const float*)d_in[2];
    const float* Wk  = (const float*)d_in[3];
    const float* Wv  = (const float*)d_in[5];
    const float* bv  = (const float*)d_in[6];
    const float* Wo  = (const float*)d_in[7];
    const float* bo  = (const float*)d_in[8];
    const float* W1  = (const float*)d_in[9];
    const float* b1  = (const float*)d_in[10];
    const float* W2  = (const float*)d_in[11];
    const float* b2  = (const float*)d_in[12];
    const float* g1  = (const float*)d_in[13];
    const float* be1 = (const float*)d_in[14];
    const float* g2  = (const float*)d_in[15];
    const float* be2 = (const float*)d_in[16];
    const int* mol    = (const int*)d_in[17];
    const int* picked = (const int*)d_in[18];
    int N = in_sizes[0] / 128;
    int noff = (N + 255) / 256;

    char* ws = (char*)d_ws;
    int*    offs = (int*)ws;                      // 513 ints (4KB slot)
    __half* WVOp = (__half*)(ws + 4096);          // packed [128][128][8] 256KB
    __half* WQKp = (__half*)(ws + 266240);        // packed [128][128][8] 256KB
    float*  bqk  = (float*)(ws + 528384);         // [8][128] 4KB
    float*  bvoP = (float*)(ws + 532480);         // [8][128] 4KB
    __half* W1p  = (__half*)(ws + 536576);        // packed [16][512][8] 128KB
    __half* W2p  = (__half*)(ws + 667648);        // packed [64][128][8] 128KB

    k_front<<<336 + noff, 256, 0, stream>>>(Wq, bq, Wk, Wv, Wo, bv, W1, W2,
                                            mol, N, noff,
                                            offs, WVOp, WQKp, bqk, bvoP, W1p, W2p);
    k_attn_tail<<<BMOL, 512, 0, stream>>>(AF, offs, picked, WQKp, bqk,
                                          WVOp, bvoP, bo, g1, be1, W1p, b1,
                                          W2p, b2, g2, be2, (float*)d_out);
}

// Round 7
// 36.049 us; speedup vs baseline: 3.9979x; 1.5816x over previous
//
#include <hip/hip_runtime.h>
#include <hip/hip_bf16.h>
#include <hip/hip_fp16.h>

// TransformerEncoderReadout: only the picked atom's output row is needed.
//   QK[b,h,:] = xp_b . WQK_h + bqk_h,   WQK_h = Wq_h . Wk_h^T  (q.bk drops out)
//   s(i,h)    = x_i . QK[b,h,:] / sqrt(128); softmax over i within molecule
//   WX[h,:]   = sum_i attn(i,h) x_i      (softmax sums to 1 -> bv folds out)
//   attn_out  = WX . WVO + (bv.Wo) + bo, WVO_h = Wv_h . Wo_h
//   out_row   = LN2(h + FFN(h)),  h = LN1(xp + attn_out)
// R7: tail K-splits are wave-uniform (LDS broadcast, kills the 7.9M 4-way
// bank conflicts of R6) and all fp16 dots use v_dot2_f32_f16.

#define BMOL 512

typedef _Float16 v2h __attribute__((ext_vector_type(2)));

#if defined(__has_builtin)
#if __has_builtin(__builtin_amdgcn_fdot2)
#define HAVE_FDOT2 1
#endif
#endif
static __device__ __forceinline__ float fdot2f(v2h a, v2h b, float c) {
#ifdef HAVE_FDOT2
    return __builtin_amdgcn_fdot2(a, b, c, false);
#else
    return c + (float)a[0] * (float)b[0] + (float)a[1] * (float)b[1];
#endif
}

// ---------------- K1 block ranges ----------------
// [0,128) WVOp | [128,256) WQKp | [256,288) W1p | [288,320) W2p
// [320,328) bvoP | [328,336) bqk | [336,336+noff) offs
__global__ __launch_bounds__(256) void k_front(
    const float* __restrict__ Wq, const float* __restrict__ bq,
    const float* __restrict__ Wk, const float* __restrict__ Wv,
    const float* __restrict__ Wo, const float* __restrict__ bv,
    const float* __restrict__ W1, const float* __restrict__ W2,
    const int* __restrict__ mol, int N, int noff,
    int* __restrict__ offs, __half* __restrict__ WVOp,
    __half* __restrict__ WQKp, float* __restrict__ bqk,
    float* __restrict__ bvoP, __half* __restrict__ W1p, __half* __restrict__ W2p)
{
    __shared__ float lds[2176];             // 2x [32][33] tiles
    int bid = blockIdx.x, t = threadIdx.x;

    if (bid < 256) {
        // ---- tiled GEMM: 32x32 output tile, K=128 ----
        // bid<128: WVO[(h*128+d)][c] = sum_kd Wv[d,h,kd]*Wo[h,kd,c]
        // else   : WQK[(h*128+k)][d] = sum_kd Wq[k,h,kd]*Wk[d,h,kd]
        bool qk = bid >= 128;
        int rel = bid & 127;
        int h = rel >> 4, tile = rel & 15;
        int dt = tile >> 2, ct = tile & 3;
        float* Avs = lds;                   // [32][33]
        float* Bos = lds + 1056;            // [32][33]
        int ry = t >> 5, cx = t & 31;
        float acc[4] = {0.f, 0.f, 0.f, 0.f};
        const float* Asrc = qk ? Wq : Wv;
        for (int kk = 0; kk < 4; ++kk) {
            int r = t >> 3, e0 = (t & 7) * 4;
            float4 va = *(const float4*)(Asrc + (size_t)(dt * 32 + r) * 1024 + h * 128 + kk * 32 + e0);
            Avs[r * 33 + e0] = va.x; Avs[r * 33 + e0 + 1] = va.y;
            Avs[r * 33 + e0 + 2] = va.z; Avs[r * 33 + e0 + 3] = va.w;
            if (qk) {                       // B[kd][d] = Wk[d,h,kd] (transposed load)
                float4 vb = *(const float4*)(Wk + (size_t)(ct * 32 + r) * 1024 + h * 128 + kk * 32 + e0);
                Bos[(e0 + 0) * 33 + r] = vb.x;
                Bos[(e0 + 1) * 33 + r] = vb.y;
                Bos[(e0 + 2) * 33 + r] = vb.z;
                Bos[(e0 + 3) * 33 + r] = vb.w;
            } else {                        // B[kd][c] = Wo[h,kd,c]
                float4 vb = *(const float4*)(Wo + (size_t)h * 16384 + (size_t)(kk * 32 + r) * 128 + ct * 32 + e0);
                Bos[r * 33 + e0] = vb.x; Bos[r * 33 + e0 + 1] = vb.y;
                Bos[r * 33 + e0 + 2] = vb.z; Bos[r * 33 + e0 + 3] = vb.w;
            }
            __syncthreads();
            #pragma unroll
            for (int k = 0; k < 32; ++k) {
                float b = Bos[k * 33 + cx];
                #pragma unroll
                for (int i = 0; i < 4; ++i) acc[i] += Avs[(ry * 4 + i) * 33 + k] * b;
            }
            __syncthreads();
        }
        // packed [k>>3][c][k&7]: k = h*128 + dt*32 + ry*4 + i; c = ct*32+cx
        __half2 p0 = __floats2half2_rn(acc[0], acc[1]);
        __half2 p1 = __floats2half2_rn(acc[2], acc[3]);
        __half* dst = (qk ? WQKp : WVOp)
                    + (size_t)(h * 16 + dt * 4 + (ry >> 1)) * 1024
                    + (ct * 32 + cx) * 8 + (ry & 1) * 4;
        ((__half2*)dst)[0] = p0; ((__half2*)dst)[1] = p1;
        return;
    }
    bid -= 256;
    if (bid < 32) {                         // W1p[(k>>3)][f][k&7], K=128, F=512
        int g = bid * 256 + t;
        int kg = g >> 9, f = g & 511;
        __half2 p[4];
        #pragma unroll
        for (int j = 0; j < 4; ++j) {
            float a = W1[(size_t)(kg * 8 + 2 * j) * 512 + f];
            float b = W1[(size_t)(kg * 8 + 2 * j + 1) * 512 + f];
            p[j] = __floats2half2_rn(a, b);
        }
        *(float4*)(W1p + (size_t)kg * 4096 + f * 8) = *(float4*)p;
        return;
    }
    bid -= 32;
    if (bid < 32) {                         // W2p[(f>>3)][c][f&7], K=512, C=128
        int g = bid * 256 + t;
        int fg = g >> 7, c = g & 127;
        __half2 p[4];
        #pragma unroll
        for (int j = 0; j < 4; ++j) {
            float a = W2[(size_t)(fg * 8 + 2 * j) * 128 + c];
            float b = W2[(size_t)(fg * 8 + 2 * j + 1) * 128 + c];
            p[j] = __floats2half2_rn(a, b);
        }
        *(float4*)(W2p + (size_t)fg * 1024 + c * 8) = *(float4*)p;
        return;
    }
    bid -= 32;
    if (bid < 8) {                          // bvoP[j][c] = sum_{hk in j-th 128} bv[hk]*Wo[hk,c]
        int half = t >> 7, c = t & 127;
        float acc = 0.f;
        #pragma unroll 4
        for (int kk = 0; kk < 64; ++kk) {
            int k = bid * 128 + half * 64 + kk;
            acc += bv[k] * Wo[(size_t)k * 128 + c];
        }
        lds[half * 128 + c] = acc;
        __syncthreads();
        if (t < 128) bvoP[bid * 128 + t] = lds[t] + lds[128 + t];
        return;
    }
    bid -= 8;
    if (bid < 8) {                          // bqk[h][d] = sum_kd bq[h,kd]*Wk[d,h,kd]
        int h = bid;
        if (t < 128) {
            const float* wk = Wk + (size_t)t * 1024 + h * 128;
            const float* bqh = bq + h * 128;
            float acc = 0.f;
            #pragma unroll 4
            for (int kd = 0; kd < 128; ++kd) acc += bqh[kd] * wk[kd];
            bqk[h * 128 + t] = acc;
        }
        return;
    }
    bid -= 8;
    {                                       // offs scan
        int i = bid * 256 + t;
        if (i < N) {
            if (i == 0) { offs[0] = 0; offs[BMOL] = N; }
            else if (mol[i] != mol[i - 1]) offs[mol[i]] = i;
        }
    }
}

// ---------------- K2: fused QK + attention + tail, one block per molecule ----------------
__global__ __launch_bounds__(512) void k_attn_tail(
    const float* __restrict__ AF, const int* __restrict__ offs,
    const int* __restrict__ picked,
    const __half* __restrict__ WQKp, const float* __restrict__ bqk,
    const __half* __restrict__ WVOp, const float* __restrict__ bvoP,
    const float* __restrict__ bo,
    const float* __restrict__ g1, const float* __restrict__ be1,
    const __half* __restrict__ W1p, const float* __restrict__ b1,
    const __half* __restrict__ W2p, const float* __restrict__ b2,
    const float* __restrict__ g2, const float* __restrict__ be2,
    float* __restrict__ out)
{
    int b = blockIdx.x, t = threadIdx.x;
    int o0 = offs[b], cnt = offs[b + 1] - o0;
    __shared__ __half xs[128][136];         // fp16 X; row = 272B = 17x16B
    __shared__ __half qsh[8][136];          // scaled QK row, fp16
    __shared__ float s[8 * 136];
    __shared__ float mh[8], lh[8];
    __shared__ float ws[2][1024];           // WX partials (i-split 2-way)
    __shared__ __half wsh[1024];            // merged WX, fp16
    __shared__ float part[4][128];          // wave-uniform K-split partials
    __shared__ float xp[128];               // picked row fp32 (residual)
    __shared__ __half xph[128];             // picked row fp16 (QK dot)
    __shared__ float h1raw[128], h1n[128];
    __shared__ __half h1nh[128];
    __shared__ __half msh[512];
    const float scale = 0.08838834764831843f;   // 1/sqrt(128)

    const float4* af4 = (const float4*)(AF + (size_t)o0 * 128);
    for (int p = t; p < cnt * 32; p += 512) {   // stage X once, f32->f16
        int i = p >> 5, d4 = p & 31;
        float4 v = af4[p];
        float2 st;
        ((__half2*)&st)[0] = __floats2half2_rn(v.x, v.y);
        ((__half2*)&st)[1] = __floats2half2_rn(v.z, v.w);
        *(float2*)(&xs[i][d4 * 4]) = st;
    }
    if (t < 128) {                          // stage picked row
        float v = AF[(size_t)(o0 + picked[b]) * 128 + t];
        xp[t] = v; xph[t] = (__half)v;
    }
    __syncthreads();
    {   // ---- QK row: qsh[h][d] = (xp . WQK_h[:,d] + bqk)*scale ----
        int h = t >> 6, d0 = (t & 63) * 2;
        const __half* wp = WQKp + ((size_t)(h * 16) * 128 + d0) * 8;
        const v2h* xh = (const v2h*)xph;
        float a0 = 0.f, a1 = 0.f;
        #pragma unroll 4
        for (int kg = 0; kg < 16; ++kg) {
            float4 r0 = *(const float4*)(wp + (size_t)kg * 1024);
            float4 r1 = *(const float4*)(wp + (size_t)kg * 1024 + 8);
            const v2h* h0 = (const v2h*)&r0;
            const v2h* h1 = (const v2h*)&r1;
            #pragma unroll
            for (int j = 0; j < 4; ++j) {
                v2h xv = xh[kg * 4 + j];
                a0 = fdot2f(xv, h0[j], a0);
                a1 = fdot2f(xv, h1[j], a1);
            }
        }
        qsh[h][d0]     = (__half)((a0 + bqk[h * 128 + d0]) * scale);
        qsh[h][d0 + 1] = (__half)((a1 + bqk[h * 128 + d0 + 1]) * scale);
    }
    __syncthreads();
    for (int p = t; p < cnt * 8; p += 512) {    // scores, fp16 dot2
        int i = p >> 3, h = p & 7;
        const float4* xr = (const float4*)xs[i];
        const float4* qr = (const float4*)qsh[h];
        float acc = 0.f;
        #pragma unroll 8
        for (int dq = 0; dq < 16; ++dq) {
            float4 xraw = xr[dq], qraw = qr[dq];
            const v2h* xh2 = (const v2h*)&xraw;
            const v2h* qh2 = (const v2h*)&qraw;
            acc = fdot2f(xh2[0], qh2[0], acc);
            acc = fdot2f(xh2[1], qh2[1], acc);
            acc = fdot2f(xh2[2], qh2[2], acc);
            acc = fdot2f(xh2[3], qh2[3], acc);
        }
        s[h * 136 + i] = acc;
    }
    __syncthreads();
    {   // softmax stats: one 64-lane wave per head
        int h = t >> 6, lane = t & 63;
        float m = -1e30f;
        for (int i = lane; i < cnt; i += 64) m = fmaxf(m, s[h * 136 + i]);
        #pragma unroll
        for (int off = 32; off; off >>= 1) m = fmaxf(m, __shfl_xor(m, off));
        float l = 0.f;
        for (int i = lane; i < cnt; i += 64) l += __expf(s[h * 136 + i] - m);
        #pragma unroll
        for (int off = 32; off; off >>= 1) l += __shfl_xor(l, off);
        if (lane == 0) { mh[h] = m; lh[h] = 1.f / l; }
    }
    __syncthreads();
    for (int p = t; p < cnt * 8; p += 512) {
        int i = p >> 3, h = p & 7;
        s[h * 136 + i] = __expf(s[h * 136 + i] - mh[h]) * lh[h];
    }
    __syncthreads();
    {   // WX partials: thread = (ih, hw, qq); i interleaved 2-way
        int ih = t >> 8, hw = (t >> 5) & 7, qq = t & 31;
        float4 a4 = {0.f, 0.f, 0.f, 0.f};
        for (int i = ih; i < cnt; i += 2) {
            float sv = s[hw * 136 + i];
            float2 xraw = *(const float2*)(&xs[i][qq * 4]);
            const __half2* xh = (const __half2*)&xraw;
            float2 x0 = __half22float2(xh[0]), x1 = __half22float2(xh[1]);
            a4.x += sv * x0.x; a4.y += sv * x0.y; a4.z += sv * x1.x; a4.w += sv * x1.y;
        }
        *(float4*)(&ws[ih][hw * 128 + qq * 4]) = a4;
    }
    __syncthreads();
    {   // merge WX partials -> fp16 (stride-2 reads: 2-way, free)
        int k0 = t * 2;
        float v0 = ws[0][k0] + ws[1][k0];
        float v1 = ws[0][k0 + 1] + ws[1][k0 + 1];
        *(__half2*)(&wsh[k0]) = __floats2half2_rn(v0, v1);
    }
    __syncthreads();
    // wave-uniform K-split: kq constant per wave -> LDS reads broadcast
    int wv = t >> 6, lane = t & 63;
    int kq = wv & 3, ch = wv >> 2;
    int c = ch * 64 + lane;
    {   // tail A: attn_out[c] = wsh . WVO[:,c], K=1024 in 4 wave-chunks
        const __half* wp = WVOp + ((size_t)(kq * 32) * 128 + c) * 8;
        const v2h* wk = (const v2h*)wsh + kq * 128;
        float acc = 0.f;
        #pragma unroll 8
        for (int g = 0; g < 32; ++g) {
            float4 raw = *(const float4*)(wp + (size_t)g * 1024);
            const v2h* hp = (const v2h*)&raw;
            acc = fdot2f(hp[0], wk[g * 4 + 0], acc);
            acc = fdot2f(hp[1], wk[g * 4 + 1], acc);
            acc = fdot2f(hp[2], wk[g * 4 + 2], acc);
            acc = fdot2f(hp[3], wk[g * 4 + 3], acc);
        }
        part[kq][c] = acc;
    }
    __syncthreads();
    if (t < 128) {
        float acc = part[0][t] + part[1][t] + part[2][t] + part[3][t];
        float bias = bo[t];
        #pragma unroll
        for (int j = 0; j < 8; ++j) bias += bvoP[j * 128 + t];
        h1raw[t] = acc + bias + xp[t];
    }
    __syncthreads();
    {   // LN1 (redundant per wave)
        int l = t & 63;
        float a = h1raw[l], bb = h1raw[l + 64];
        float sm = a + bb, sq = a * a + bb * bb;
        #pragma unroll
        for (int off = 32; off; off >>= 1) { sm += __shfl_xor(sm, off); sq += __shfl_xor(sq, off); }
        float m = sm * (1.f / 128.f), var = sq * (1.f / 128.f) - m * m;
        float rs = rsqrtf(var + 1e-3f);
        if (t < 128) {
            float v = (h1raw[t] - m) * rs * g1[t] + be1[t];
            h1n[t] = v; h1nh[t] = (__half)v;
        }
    }
    __syncthreads();
    {   // phase B: msh[f] = relu(h1nh . W1[:,f] + b1), one output per thread
        const __half* wp = W1p + t * 8;
        const v2h* hk = (const v2h*)h1nh;
        float acc = 0.f;
        #pragma unroll 8
        for (int kg = 0; kg < 16; ++kg) {
            float4 raw = *(const float4*)(wp + (size_t)kg * 4096);
            const v2h* hp = (const v2h*)&raw;
            acc = fdot2f(hp[0], hk[kg * 4 + 0], acc);
            acc = fdot2f(hp[1], hk[kg * 4 + 1], acc);
            acc = fdot2f(hp[2], hk[kg * 4 + 2], acc);
            acc = fdot2f(hp[3], hk[kg * 4 + 3], acc);
        }
        msh[t] = (__half)fmaxf(acc + b1[t], 0.f);
    }
    __syncthreads();
    {   // phase C: out[c] = msh . W2[:,c] + b2 + h1n, K=512 in 4 wave-chunks
        const __half* wp = W2p + ((size_t)(kq * 16) * 128 + c) * 8;
        const v2h* mk = (const v2h*)msh + kq * 64;
        float acc = 0.f;
        #pragma unroll 8
        for (int g = 0; g < 16; ++g) {
            float4 raw = *(const float4*)(wp + (size_t)g * 1024);
            const v2h* hp = (const v2h*)&raw;
            acc = fdot2f(hp[0], mk[g * 4 + 0], acc);
            acc = fdot2f(hp[1], mk[g * 4 + 1], acc);
            acc = fdot2f(hp[2], mk[g * 4 + 2], acc);
            acc = fdot2f(hp[3], mk[g * 4 + 3], acc);
        }
        part[kq][c] = acc;
    }
    __syncthreads();
    if (t < 128) {
        float acc = part[0][t] + part[1][t] + part[2][t] + part[3][t];
        h1raw[t] = acc + b2[t] + h1n[t];
    }
    __syncthreads();
    {   // LN2 (redundant per wave) -> global out
        int l = t & 63;
        float a = h1raw[l], bb = h1raw[l + 64];
        float sm = a + bb, sq = a * a + bb * bb;
        #pragma unroll
        for (int off = 32; off; off >>= 1) { sm += __shfl_xor(sm, off); sq += __shfl_xor(sq, off); }
        float m = sm * (1.f / 128.f), var = sq * (1.f / 128.f) - m * m;
        float rs = rsqrtf(var + 1e-3f);
        if (t < 128) out[(size_t)b * 128 + t] = (h1raw[t] - m) * rs * g2[t] + be2[t];
    }
}

extern "C" void kernel_launch(void* const* d_in, const int* in_sizes, int n_in,
                              void* d_out, int out_size, void* d_ws, size_t ws_size,
                              hipStream_t stream) {
    const float* AF  = (const float*)d_in[0];
    const float* Wq  = (const float*)d_in[1];
    const float* bq  = (const float*)d_in[2];
    const float* Wk  = (const float*)d_in[3];
    const float* Wv  = (const float*)d_in[5];
    const float* bv  = (const float*)d_in[6];
    const float* Wo  = (const float*)d_in[7];
    const float* bo  = (const float*)d_in[8];
    const float* W1  = (const float*)d_in[9];
    const float* b1  = (const float*)d_in[10];
    const float* W2  = (const float*)d_in[11];
    const float* b2  = (const float*)d_in[12];
    const float* g1  = (const float*)d_in[13];
    const float* be1 = (const float*)d_in[14];
    const float* g2  = (const float*)d_in[15];
    const float* be2 = (const float*)d_in[16];
    const int* mol    = (const int*)d_in[17];
    const int* picked = (const int*)d_in[18];
    int N = in_sizes[0] / 128;
    int noff = (N + 255) / 256;

    char* ws = (char*)d_ws;
    int*    offs = (int*)ws;                      // 513 ints (4KB slot)
    __half* WVOp = (__half*)(ws + 4096);          // packed [128][128][8] 256KB
    __half* WQKp = (__half*)(ws + 266240);        // packed [128][128][8] 256KB
    float*  bqk  = (float*)(ws + 528384);         // [8][128] 4KB
    float*  bvoP = (float*)(ws + 532480);         // [8][128] 4KB
    __half* W1p  = (__half*)(ws + 536576);        // packed [16][512][8] 128KB
    __half* W2p  = (__half*)(ws + 667648);        // packed [64][128][8] 128KB

    k_front<<<336 + noff, 256, 0, stream>>>(Wq, bq, Wk, Wv, Wo, bv, W1, W2,
                                            mol, N, noff,
                                            offs, WVOp, WQKp, bqk, bvoP, W1p, W2p);
    k_attn_tail<<<BMOL, 512, 0, stream>>>(AF, offs, picked, WQKp, bqk,
                                          WVOp, bvoP, bo, g1, be1, W1p, b1,
                                          W2p, b2, g2, be2, (float*)d_out);
}